// Round 1
// baseline (10309.601 us; speedup 1.0000x reference)
//
#include <hip/hip_runtime.h>
#include <hip/hip_bf16.h>
#include <math.h>

// ---------------------------------------------------------------- constants
#define BB 2
#define TT 1024
#define DD 1024
#define HH 16
#define KVH 4
#define HDIM 64
#define VV 32768
#define DFF 4096

#define ACT_NONE 0
#define ACT_RELU2 1
#define ACT_SILU 2
#define ACT_SIG 3

// ---------------------------------------------------------------- rope tables
__global__ __launch_bounds__(256) void rope_tab_k(float* __restrict__ cosT,
                                                  float* __restrict__ sinT) {
  int idx = blockIdx.x * 256 + threadIdx.x;   // T*32 = 32768 total
  int t = idx >> 5, j = idx & 31;
  float inv = 1.0f / powf(10000.0f, (float)(2 * j) * (1.0f / 64.0f));
  float fr = (float)t * inv;
  cosT[idx] = cosf(fr);
  sinT[idx] = sinf(fr);
}

// ---------------------------------------------------------------- embedding gather
__global__ __launch_bounds__(256) void embed_k(const int* __restrict__ tok,
                                               const float* __restrict__ emb,
                                               float* __restrict__ X) {
  int row = blockIdx.x;          // B*T rows
  int tid = threadIdx.x;
  int tk = tok[row];
  float4 v = *reinterpret_cast<const float4*>(emb + (size_t)tk * DD + tid * 4);
  *reinterpret_cast<float4*>(X + (size_t)row * DD + tid * 4) = v;
}

// ---------------------------------------------------------------- rmsnorm over D=1024
__global__ __launch_bounds__(256) void rmsnorm_k(const float* __restrict__ in,
                                                 float* __restrict__ out) {
  int row = blockIdx.x;
  int tid = threadIdx.x;
  const float* p = in + (size_t)row * DD;
  float4 v = *reinterpret_cast<const float4*>(p + tid * 4);
  float ss = v.x * v.x + v.y * v.y + v.z * v.z + v.w * v.w;
#pragma unroll
  for (int m = 1; m < 64; m <<= 1) ss += __shfl_xor(ss, m, 64);
  __shared__ float wsum[4];
  int wid = tid >> 6, lane = tid & 63;
  if (lane == 0) wsum[wid] = ss;
  __syncthreads();
  float tot = wsum[0] + wsum[1] + wsum[2] + wsum[3];
  float sc = rsqrtf(tot * (1.0f / 1024.0f) + 1e-6f);
  float4 o;
  o.x = v.x * sc; o.y = v.y * sc; o.z = v.z * sc; o.w = v.w * sc;
  *reinterpret_cast<float4*>(out + (size_t)row * DD + tid * 4) = o;
}

// ---------------------------------------------------------------- generic SGEMM: C = [res +] act(A @ W^T)
// A: (M,K) row-major. W: (N,K) row-major. C: (M,*) with leading dim ldC.
__global__ __launch_bounds__(256) void sgemm_k(const float* __restrict__ A,
                                               const float* __restrict__ W,
                                               float* __restrict__ C,
                                               int M, int N, int K, int ldC,
                                               int act, int res) {
  __shared__ float As[16][65];
  __shared__ float Ws[16][65];
  const int bm = blockIdx.y * 64;
  const int bn = blockIdx.x * 64;
  const int tid = threadIdx.x;
  const int tx = tid & 15, ty = tid >> 4;
  const int lr = tid >> 2;          // 0..63
  const int lc = (tid & 3) * 4;     // 0,4,8,12
  float acc[4][4] = {{0.f}};
  for (int k0 = 0; k0 < K; k0 += 16) {
    int arow = bm + lr;
    float4 av = make_float4(0.f, 0.f, 0.f, 0.f);
    if (arow < M) av = *reinterpret_cast<const float4*>(A + (size_t)arow * K + k0 + lc);
    As[lc + 0][lr] = av.x; As[lc + 1][lr] = av.y; As[lc + 2][lr] = av.z; As[lc + 3][lr] = av.w;
    int wrow = bn + lr;
    float4 wv = make_float4(0.f, 0.f, 0.f, 0.f);
    if (wrow < N) wv = *reinterpret_cast<const float4*>(W + (size_t)wrow * K + k0 + lc);
    Ws[lc + 0][lr] = wv.x; Ws[lc + 1][lr] = wv.y; Ws[lc + 2][lr] = wv.z; Ws[lc + 3][lr] = wv.w;
    __syncthreads();
#pragma unroll
    for (int kk = 0; kk < 16; ++kk) {
      float a[4], b[4];
#pragma unroll
      for (int i = 0; i < 4; ++i) a[i] = As[kk][ty * 4 + i];
#pragma unroll
      for (int j = 0; j < 4; ++j) b[j] = Ws[kk][tx * 4 + j];
#pragma unroll
      for (int i = 0; i < 4; ++i)
#pragma unroll
        for (int j = 0; j < 4; ++j) acc[i][j] += a[i] * b[j];
    }
    __syncthreads();
  }
#pragma unroll
  for (int i = 0; i < 4; ++i) {
    int row = bm + ty * 4 + i;
    if (row >= M) continue;
#pragma unroll
    for (int j = 0; j < 4; ++j) {
      int col = bn + tx * 4 + j;
      if (col >= N) continue;
      float v = acc[i][j];
      if (act == ACT_RELU2) { v = fmaxf(v, 0.f); v = v * v; }
      else if (act == ACT_SILU) { v = v / (1.f + expf(-v)); }
      else if (act == ACT_SIG) { v = 1.f / (1.f + expf(-v)); }
      float* cp = C + (size_t)row * ldC + col;
      if (res) v += *cp;
      *cp = v;
    }
  }
}

// ---------------------------------------------------------------- l2norm (+gain) (+rope) on rows of 64
// P: (B,T,NH,64) flat. one wave per row.
__global__ __launch_bounds__(256) void l2n_rope_k(float* __restrict__ P, int NH,
                                                  const float* __restrict__ gain,
                                                  const float* __restrict__ cosT,
                                                  const float* __restrict__ sinT,
                                                  int do_rope) {
  int row = blockIdx.x * 4 + (threadIdx.x >> 6);
  int lane = threadIdx.x & 63;
  size_t idx = (size_t)row * 64 + lane;
  float val = P[idx];
  float ss = val * val;
#pragma unroll
  for (int m = 1; m < 64; m <<= 1) ss += __shfl_xor(ss, m, 64);
  val = val / fmaxf(sqrtf(ss), 1e-6f);
  int hh = row % NH;
  int t = (row / NH) & (TT - 1);
  if (gain) val *= gain[hh];
  if (do_rope) {
    float pr = __shfl_xor(val, 32, 64);
    int jj = lane & 31;
    float c = cosT[t * 32 + jj];
    float s = sinT[t * 32 + jj];
    val = (lane < 32) ? (val * c + pr * s) : (val * c - pr * s);
  }
  P[idx] = val;
}

// ---------------------------------------------------------------- causal attention, 16 queries/block
// Q: (B,T,H*64), K/V: (B,T,KV*64), O: (B,T,H*64)
__global__ __launch_bounds__(256) void attn_k(const float* __restrict__ Q,
                                              const float* __restrict__ K,
                                              const float* __restrict__ V,
                                              float* __restrict__ O) {
  __shared__ float Qs[16][65];
  __shared__ float Ks[64][65];
  __shared__ float Vs[64][65];
  __shared__ float Ps[16][65];
  const int q0 = blockIdx.x * 16;
  const int bh = blockIdx.y;
  const int b = bh >> 4, hh = bh & 15;
  const int kvh = hh >> 2;
  const int tid = threadIdx.x;
  {
    int r = tid >> 4;
    int c = (tid & 15) * 4;
    const float* src = Q + ((size_t)(b * TT + q0 + r) * (HH * 64)) + hh * 64 + c;
    float4 v = *reinterpret_cast<const float4*>(src);
    Qs[r][c] = v.x; Qs[r][c + 1] = v.y; Qs[r][c + 2] = v.z; Qs[r][c + 3] = v.w;
  }
  const int q = tid >> 4;
  const int kb4 = (tid & 15) * 4;
  const int qt = q0 + q;
  float o0 = 0.f, o1 = 0.f, o2 = 0.f, o3 = 0.f;
  float denom = 0.f;
  for (int kc = 0; kc <= q0 + 15; kc += 64) {
#pragma unroll
    for (int i = 0; i < 4; ++i) {
      int rr = (tid >> 4) + i * 16;
      int cc = (tid & 15) * 4;
      size_t kidx = ((size_t)(b * TT + kc + rr) * (KVH * 64)) + kvh * 64 + cc;
      float4 kv = *reinterpret_cast<const float4*>(K + kidx);
      Ks[rr][cc] = kv.x; Ks[rr][cc + 1] = kv.y; Ks[rr][cc + 2] = kv.z; Ks[rr][cc + 3] = kv.w;
      float4 vv = *reinterpret_cast<const float4*>(V + kidx);
      Vs[rr][cc] = vv.x; Vs[rr][cc + 1] = vv.y; Vs[rr][cc + 2] = vv.z; Vs[rr][cc + 3] = vv.w;
    }
    __syncthreads();
    float psum = 0.f;
#pragma unroll
    for (int j = 0; j < 4; ++j) {
      int kk = kb4 + j;
      int kglob = kc + kk;
      float s = 0.f;
#pragma unroll
      for (int d = 0; d < 64; ++d) s += Qs[q][d] * Ks[kk][d];
      // scores bounded in [-1.5,1.5] (l2n'ed q*1.5, l2n'ed k) -> exp safe without max-sub
      float pp = (kglob <= qt) ? expf(s) : 0.f;
      Ps[q][kk] = pp;
      psum += pp;
    }
#pragma unroll
    for (int m = 1; m < 16; m <<= 1) psum += __shfl_xor(psum, m, 64);
    denom += psum;
    __syncthreads();
#pragma unroll 8
    for (int kk = 0; kk < 64; ++kk) {
      float pp = Ps[q][kk];
      o0 += pp * Vs[kk][kb4 + 0];
      o1 += pp * Vs[kk][kb4 + 1];
      o2 += pp * Vs[kk][kb4 + 2];
      o3 += pp * Vs[kk][kb4 + 3];
    }
    __syncthreads();
  }
  float invd = 1.0f / denom;
  size_t oidx = ((size_t)(b * TT + qt) * (HH * 64)) + hh * 64 + kb4;
  float4 ov;
  ov.x = o0 * invd; ov.y = o1 * invd; ov.z = o2 * invd; ov.w = o3 * invd;
  *reinterpret_cast<float4*>(O + oidx) = ov;
}

// ---------------------------------------------------------------- causal depthwise conv (CK=4) + silu + split
__global__ __launch_bounds__(256) void conv_k(const float* __restrict__ X,
                                              const float* __restrict__ Wc,
                                              float* __restrict__ Qo,
                                              float* __restrict__ Ko,
                                              float* __restrict__ Vo) {
  int idx = blockIdx.x * 256 + threadIdx.x;   // B*T*3072 exact
  int c = idx % 3072;
  int rest = idx / 3072;
  int t = rest & (TT - 1);
  int b = rest >> 10;
  const float* w = Wc + c * 4;
  float acc = 0.f;
#pragma unroll
  for (int j = 0; j < 4; ++j) {
    int tt = t - 3 + j;
    if (tt >= 0) acc += w[j] * X[((size_t)(b * TT + tt)) * 3072 + c];
  }
  float y = acc / (1.f + expf(-acc));   // silu
  int which = c >> 10, cc = c & 1023;
  float* dst = (which == 0) ? Qo : ((which == 1) ? Ko : Vo);
  dst[((size_t)(b * TT + t)) * 1024 + cc] = y;
}

// ---------------------------------------------------------------- GDN scan: one wave per (b,h,v-column)
// layouts: Qg/Kg/Vg/Og: (B,T,H*64); Al/Be: (B,T,H)
__global__ __launch_bounds__(256) void gdn_scan_k(const float* __restrict__ Qg,
                                                  const float* __restrict__ Kg,
                                                  const float* __restrict__ Vg,
                                                  const float* __restrict__ Al,
                                                  const float* __restrict__ Be,
                                                  float* __restrict__ Og) {
  const int bh = blockIdx.x >> 4;        // b*16+h
  const int vblk = blockIdx.x & 15;
  const int wid = threadIdx.x >> 6;
  const int lane = threadIdx.x & 63;
  const int v = vblk * 4 + wid;
  const int b = bh >> 4, hh = bh & 15;
  float S = 0.f;
  size_t p = (size_t)b * TT * 1024 + hh * 64;
  size_t ab = (size_t)b * TT * HH + hh;
  float kd = Kg[p + lane], qd = Qg[p + lane], vv = Vg[p + v];
  float a = Al[ab], bt = Be[ab];
  for (int t = 0; t < TT; ++t) {
    float kdn = 0.f, qdn = 0.f, vvn = 0.f, an = 0.f, btn = 0.f;
    if (t < TT - 1) {
      size_t pn = p + 1024;
      kdn = Kg[pn + lane]; qdn = Qg[pn + lane]; vvn = Vg[pn + v];
      an = Al[ab + HH]; btn = Be[ab + HH];
    }
    float ks = kd * S;
#pragma unroll
    for (int m = 1; m < 64; m <<= 1) ks += __shfl_xor(ks, m, 64);
    S = a * (S - bt * kd * ks) + kd * vv;
    float o = qd * S;
#pragma unroll
    for (int m = 1; m < 64; m <<= 1) o += __shfl_xor(o, m, 64);
    if (lane == 0) Og[p + v] = o;
    p += 1024; ab += HH;
    kd = kdn; qd = qdn; vv = vvn; a = an; bt = btn;
  }
}

// ---------------------------------------------------------------- rmsnorm over 64 * gate (in place)
__global__ __launch_bounds__(256) void rms64_mul_k(float* __restrict__ O,
                                                   const float* __restrict__ G) {
  int row = blockIdx.x * 4 + (threadIdx.x >> 6);
  int lane = threadIdx.x & 63;
  size_t idx = (size_t)row * 64 + lane;
  float val = O[idx];
  float ss = val * val;
#pragma unroll
  for (int m = 1; m < 64; m <<= 1) ss += __shfl_xor(ss, m, 64);
  float sc = rsqrtf(ss * (1.0f / 64.0f) + 1e-6f);
  O[idx] = val * sc * G[idx];
}

// ---------------------------------------------------------------- host-side launch
static inline void gemm(hipStream_t s, const float* A, const float* W, float* C,
                        int M, int N, int K, int ldC, int act, int res) {
  dim3 g((N + 63) / 64, (M + 63) / 64);
  sgemm_k<<<g, 256, 0, s>>>(A, W, C, M, N, K, ldC, act, res);
}

extern "C" void kernel_launch(void* const* d_in, const int* in_sizes, int n_in,
                              void* d_out, int out_size, void* d_ws, size_t ws_size,
                              hipStream_t stream) {
  const int*   tokens = (const int*)d_in[0];
  const float* emb    = (const float*)d_in[1];
  const float* aw_q   = (const float*)d_in[2];
  const float* aw_k   = (const float*)d_in[3];
  const float* aw_v   = (const float*)d_in[4];
  const float* aw_o   = (const float*)d_in[5];
  const float* a_gain = (const float*)d_in[6];
  const float* a_m1   = (const float*)d_in[7];
  const float* a_m2   = (const float*)d_in[8];
  const float* g_wq   = (const float*)d_in[9];
  const float* g_wk   = (const float*)d_in[10];
  const float* g_wv   = (const float*)d_in[11];
  const float* g_wa   = (const float*)d_in[12];
  const float* g_wb   = (const float*)d_in[13];
  const float* g_wg   = (const float*)d_in[14];
  const float* g_wo   = (const float*)d_in[15];
  const float* g_conv = (const float*)d_in[16];
  const float* g_m1   = (const float*)d_in[17];
  const float* g_m2   = (const float*)d_in[18];

  const int M = BB * TT;  // 2048

  float* ws = (float*)d_ws;
  float* x    = ws;                  // 2097152
  float* h    = x + 2097152;         // 2097152
  float* qb   = h + 2097152;         // 2097152 (attn q)
  float* kb   = qb + 2097152;        // 524288  (attn k)
  float* vb   = kb + 524288;         // 524288  (attn v)
  float* qg   = vb + 524288;         // 2097152 (gdn q / attn o_flat)
  float* kg   = qg + 2097152;        // 2097152
  float* vg   = kg + 2097152;        // 2097152
  float* og   = vg + 2097152;        // 2097152
  float* gb   = og + 2097152;        // 2097152
  float* alp  = gb + 2097152;        // 32768
  float* bet  = alp + 32768;         // 32768
  float* cosT = bet + 32768;         // 32768
  float* sinT = cosT + 32768;        // 32768
  // total ws usage ~ 71.8 MB

  // big scratch lives in d_out (fully rewritten by the final logits GEMM)
  float* outF = (float*)d_out;
  float* mid  = outF;                // 8388608  (B*T*DFF)
  float* qkv  = outF + 8388608;      // 6291456  (B*T*3072)

  rope_tab_k<<<128, 256, 0, stream>>>(cosT, sinT);
  embed_k<<<M, 256, 0, stream>>>(tokens, emb, x);

  for (int i = 0; i < 2; ++i) {
    const float* wq = aw_q + (size_t)i * 1024 * 1024;
    const float* wk = aw_k + (size_t)i * 256 * 1024;
    const float* wv = aw_v + (size_t)i * 256 * 1024;
    const float* wo = aw_o + (size_t)i * 1024 * 1024;
    const float* gn = a_gain + (size_t)i * 16;
    const float* m1 = a_m1 + (size_t)i * 4096 * 1024;
    const float* m2 = a_m2 + (size_t)i * 1024 * 4096;
    const float* zq = g_wq + (size_t)i * 1024 * 1024;
    const float* zk = g_wk + (size_t)i * 1024 * 1024;
    const float* zv = g_wv + (size_t)i * 1024 * 1024;
    const float* za = g_wa + (size_t)i * 16 * 1024;
    const float* zb = g_wb + (size_t)i * 16 * 1024;
    const float* zg = g_wg + (size_t)i * 1024 * 1024;
    const float* zo = g_wo + (size_t)i * 1024 * 1024;
    const float* zc = g_conv + (size_t)i * 3072 * 4;
    const float* n1 = g_m1 + (size_t)i * 4096 * 1024;
    const float* n2 = g_m2 + (size_t)i * 1024 * 4096;

    // ---------------- attention block ----------------
    rmsnorm_k<<<M, 256, 0, stream>>>(x, h);
    gemm(stream, h, wq, qb, M, 1024, 1024, 1024, ACT_NONE, 0);
    gemm(stream, h, wk, kb, M, 256, 1024, 256, ACT_NONE, 0);
    gemm(stream, h, wv, vb, M, 256, 1024, 256, ACT_NONE, 0);
    l2n_rope_k<<<(M * HH) / 4, 256, 0, stream>>>(qb, HH, gn, cosT, sinT, 1);
    l2n_rope_k<<<(M * KVH) / 4, 256, 0, stream>>>(kb, KVH, nullptr, cosT, sinT, 1);
    attn_k<<<dim3(TT / 16, BB * HH), 256, 0, stream>>>(qb, kb, vb, qg);
    gemm(stream, qg, wo, x, M, 1024, 1024, 1024, ACT_NONE, 1);
    rmsnorm_k<<<M, 256, 0, stream>>>(x, h);
    gemm(stream, h, m1, mid, M, DFF, 1024, DFF, ACT_RELU2, 0);
    gemm(stream, mid, m2, x, M, 1024, DFF, 1024, ACT_NONE, 1);

    // ---------------- GDN block ----------------
    rmsnorm_k<<<M, 256, 0, stream>>>(x, h);
    gemm(stream, h, zq, qkv + 0,    M, 1024, 1024, 3072, ACT_NONE, 0);
    gemm(stream, h, zk, qkv + 1024, M, 1024, 1024, 3072, ACT_NONE, 0);
    gemm(stream, h, zv, qkv + 2048, M, 1024, 1024, 3072, ACT_NONE, 0);
    conv_k<<<(M * 3072) / 256, 256, 0, stream>>>(qkv, zc, qg, kg, vg);
    l2n_rope_k<<<(M * HH) / 4, 256, 0, stream>>>(qg, HH, nullptr, nullptr, nullptr, 0);
    l2n_rope_k<<<(M * HH) / 4, 256, 0, stream>>>(kg, HH, nullptr, nullptr, nullptr, 0);
    gemm(stream, h, za, alp, M, 16, 1024, 16, ACT_SIG, 0);
    gemm(stream, h, zb, bet, M, 16, 1024, 16, ACT_SIG, 0);
    gdn_scan_k<<<BB * HH * 16, 256, 0, stream>>>(qg, kg, vg, alp, bet, og);
    gemm(stream, h, zg, gb, M, 1024, 1024, 1024, ACT_SILU, 0);
    rms64_mul_k<<<(M * HH) / 4, 256, 0, stream>>>(og, gb);
    gemm(stream, og, zo, x, M, 1024, 1024, 1024, ACT_NONE, 1);
    rmsnorm_k<<<M, 256, 0, stream>>>(x, h);
    gemm(stream, h, n1, mid, M, DFF, 1024, DFF, ACT_RELU2, 0);
    gemm(stream, mid, n2, x, M, 1024, DFF, 1024, ACT_NONE, 1);
  }

  // ---------------- final logits ----------------
  rmsnorm_k<<<M, 256, 0, stream>>>(x, h);
  gemm(stream, h, emb, outF, M, VV, 1024, VV, ACT_NONE, 0);
}

// Round 2
// 5084.143 us; speedup vs baseline: 2.0278x; 2.0278x over previous
//
#include <hip/hip_runtime.h>
#include <hip/hip_bf16.h>
#include <math.h>

// ---------------------------------------------------------------- constants
#define BB 2
#define TT 1024
#define DD 1024
#define HH 16
#define KVH 4
#define HDIM 64
#define VV 32768
#define DFF 4096

#define ACT_NONE 0
#define ACT_RELU2 1
#define ACT_SILU 2
#define ACT_SIG 3

typedef __attribute__((ext_vector_type(8))) short short8v;
typedef __attribute__((ext_vector_type(4))) float f32x4;

__device__ inline ushort f2bf(float f) {
  uint u = __float_as_uint(f);
  uint r = u + 0x7FFFu + ((u >> 16) & 1u);
  return (ushort)(r >> 16);
}
__device__ inline uint pack2(float lo, float hi) {
  return (uint)f2bf(lo) | ((uint)f2bf(hi) << 16);
}

// ---------------------------------------------------------------- rope tables
__global__ __launch_bounds__(256) void rope_tab_k(float* __restrict__ cosT,
                                                  float* __restrict__ sinT) {
  int idx = blockIdx.x * 256 + threadIdx.x;   // T*32 = 32768 total
  int t = idx >> 5, j = idx & 31;
  float inv = 1.0f / powf(10000.0f, (float)(2 * j) * (1.0f / 64.0f));
  float fr = (float)t * inv;
  cosT[idx] = cosf(fr);
  sinT[idx] = sinf(fr);
}

// ---------------------------------------------------------------- embedding gather
__global__ __launch_bounds__(256) void embed_k(const int* __restrict__ tok,
                                               const float* __restrict__ emb,
                                               float* __restrict__ X) {
  int row = blockIdx.x;          // B*T rows
  int tid = threadIdx.x;
  int tk = tok[row];
  float4 v = *reinterpret_cast<const float4*>(emb + (size_t)tk * DD + tid * 4);
  *reinterpret_cast<float4*>(X + (size_t)row * DD + tid * 4) = v;
}

// ---------------------------------------------------------------- rmsnorm over D=1024
__global__ __launch_bounds__(256) void rmsnorm_k(const float* __restrict__ in,
                                                 float* __restrict__ out) {
  int row = blockIdx.x;
  int tid = threadIdx.x;
  const float* p = in + (size_t)row * DD;
  float4 v = *reinterpret_cast<const float4*>(p + tid * 4);
  float ss = v.x * v.x + v.y * v.y + v.z * v.z + v.w * v.w;
#pragma unroll
  for (int m = 1; m < 64; m <<= 1) ss += __shfl_xor(ss, m, 64);
  __shared__ float wsum[4];
  int wid = tid >> 6, lane = tid & 63;
  if (lane == 0) wsum[wid] = ss;
  __syncthreads();
  float tot = wsum[0] + wsum[1] + wsum[2] + wsum[3];
  float sc = rsqrtf(tot * (1.0f / 1024.0f) + 1e-6f);
  float4 o;
  o.x = v.x * sc; o.y = v.y * sc; o.z = v.z * sc; o.w = v.w * sc;
  *reinterpret_cast<float4*>(out + (size_t)row * DD + tid * 4) = o;
}

// ---------------------------------------------------------------- MFMA bf16 GEMM: C = [res +] act(A @ W^T)
// A:(M,K) f32 row-major, W:(N,K) f32 row-major. M%128==0, N%128==0, K%32==0.
// 128x128 tile, BK=32, 4 waves 2x2, each wave 64x64 = 4x4 frags of 16x16x32.
__global__ __launch_bounds__(256) void mfma_gemm_k(const float* __restrict__ A,
                                                   const float* __restrict__ W,
                                                   float* __restrict__ C,
                                                   int M, int N, int K, int ldC,
                                                   int act, int res) {
  __shared__ ushort As[128 * 40];   // row stride 40 bf16 (80B) to spread banks
  __shared__ ushort Ws[128 * 40];
  const int bm = blockIdx.y * 128;
  const int bn = blockIdx.x * 128;
  const int tid = threadIdx.x;
  const int wave = tid >> 6, lane = tid & 63;
  const int wr = wave >> 1, wc = wave & 1;
  const int lr = lane & 15, lk = (lane >> 4) * 8;   // frag row-in-tile, k-base

  // staging indices: 4 passes, thread -> (row = p*32 + tid>>3, col4 = (tid&7)*4)
  const int srow = tid >> 3;        // 0..31
  const int scol = (tid & 7) * 4;   // 0..28

  f32x4 acc[4][4] = {};

  for (int k0 = 0; k0 < K; k0 += 32) {
#pragma unroll
    for (int p = 0; p < 4; ++p) {
      int row = p * 32 + srow;
      float4 av = *reinterpret_cast<const float4*>(A + (size_t)(bm + row) * K + k0 + scol);
      uint2 aw; aw.x = pack2(av.x, av.y); aw.y = pack2(av.z, av.w);
      *reinterpret_cast<uint2*>(&As[row * 40 + scol]) = aw;
      float4 wv = *reinterpret_cast<const float4*>(W + (size_t)(bn + row) * K + k0 + scol);
      uint2 ww; ww.x = pack2(wv.x, wv.y); ww.y = pack2(wv.z, wv.w);
      *reinterpret_cast<uint2*>(&Ws[row * 40 + scol]) = ww;
    }
    __syncthreads();
    short8v av[4], bv[4];
#pragma unroll
    for (int m = 0; m < 4; ++m)
      av[m] = *reinterpret_cast<const short8v*>(&As[(wr * 64 + m * 16 + lr) * 40 + lk]);
#pragma unroll
    for (int n = 0; n < 4; ++n)
      bv[n] = *reinterpret_cast<const short8v*>(&Ws[(wc * 64 + n * 16 + lr) * 40 + lk]);
#pragma unroll
    for (int m = 0; m < 4; ++m)
#pragma unroll
      for (int n = 0; n < 4; ++n)
        acc[m][n] = __builtin_amdgcn_mfma_f32_16x16x32_bf16(av[m], bv[n], acc[m][n], 0, 0, 0);
    __syncthreads();
  }

  // epilogue: D row = (lane>>4)*4 + j, col = lane&15 (verified layout)
  const int rj = (lane >> 4) * 4;
#pragma unroll
  for (int m = 0; m < 4; ++m) {
    int rowb = bm + wr * 64 + m * 16 + rj;
#pragma unroll
    for (int n = 0; n < 4; ++n) {
      int col = bn + wc * 64 + n * 16 + lr;
#pragma unroll
      for (int j = 0; j < 4; ++j) {
        float v = acc[m][n][j];
        if (act == ACT_RELU2) { v = fmaxf(v, 0.f); v = v * v; }
        else if (act == ACT_SILU) { v = v / (1.f + expf(-v)); }
        float* cp = C + (size_t)(rowb + j) * ldC + col;
        if (res) v += *cp;
        *cp = v;
      }
    }
  }
}

// ---------------------------------------------------------------- fp32 SGEMM (small N fallback)
__global__ __launch_bounds__(256) void sgemm_k(const float* __restrict__ A,
                                               const float* __restrict__ W,
                                               float* __restrict__ C,
                                               int M, int N, int K, int ldC,
                                               int act, int res) {
  __shared__ float Asm[16][65];
  __shared__ float Wsm[16][65];
  const int bm = blockIdx.y * 64;
  const int bn = blockIdx.x * 64;
  const int tid = threadIdx.x;
  const int tx = tid & 15, ty = tid >> 4;
  const int lr = tid >> 2;          // 0..63
  const int lc = (tid & 3) * 4;     // 0,4,8,12
  float acc[4][4] = {{0.f}};
  for (int k0 = 0; k0 < K; k0 += 16) {
    int arow = bm + lr;
    float4 av = make_float4(0.f, 0.f, 0.f, 0.f);
    if (arow < M) av = *reinterpret_cast<const float4*>(A + (size_t)arow * K + k0 + lc);
    Asm[lc + 0][lr] = av.x; Asm[lc + 1][lr] = av.y; Asm[lc + 2][lr] = av.z; Asm[lc + 3][lr] = av.w;
    int wrow = bn + lr;
    float4 wv = make_float4(0.f, 0.f, 0.f, 0.f);
    if (wrow < N) wv = *reinterpret_cast<const float4*>(W + (size_t)wrow * K + k0 + lc);
    Wsm[lc + 0][lr] = wv.x; Wsm[lc + 1][lr] = wv.y; Wsm[lc + 2][lr] = wv.z; Wsm[lc + 3][lr] = wv.w;
    __syncthreads();
#pragma unroll
    for (int kk = 0; kk < 16; ++kk) {
      float a[4], b[4];
#pragma unroll
      for (int i = 0; i < 4; ++i) a[i] = Asm[kk][ty * 4 + i];
#pragma unroll
      for (int j = 0; j < 4; ++j) b[j] = Wsm[kk][tx * 4 + j];
#pragma unroll
      for (int i = 0; i < 4; ++i)
#pragma unroll
        for (int j = 0; j < 4; ++j) acc[i][j] += a[i] * b[j];
    }
    __syncthreads();
  }
#pragma unroll
  for (int i = 0; i < 4; ++i) {
    int row = bm + ty * 4 + i;
    if (row >= M) continue;
#pragma unroll
    for (int j = 0; j < 4; ++j) {
      int col = bn + tx * 4 + j;
      if (col >= N) continue;
      float v = acc[i][j];
      if (act == ACT_RELU2) { v = fmaxf(v, 0.f); v = v * v; }
      else if (act == ACT_SILU) { v = v / (1.f + expf(-v)); }
      else if (act == ACT_SIG) { v = 1.f / (1.f + expf(-v)); }
      float* cp = C + (size_t)row * ldC + col;
      if (res) v += *cp;
      *cp = v;
    }
  }
}

// ---------------------------------------------------------------- l2norm (+gain) (+rope) on rows of 64
__global__ __launch_bounds__(256) void l2n_rope_k(float* __restrict__ P, int NH,
                                                  const float* __restrict__ gain,
                                                  const float* __restrict__ cosT,
                                                  const float* __restrict__ sinT,
                                                  int do_rope) {
  int row = blockIdx.x * 4 + (threadIdx.x >> 6);
  int lane = threadIdx.x & 63;
  size_t idx = (size_t)row * 64 + lane;
  float val = P[idx];
  float ss = val * val;
#pragma unroll
  for (int m = 1; m < 64; m <<= 1) ss += __shfl_xor(ss, m, 64);
  val = val / fmaxf(sqrtf(ss), 1e-6f);
  int hh = row % NH;
  int t = (row / NH) & (TT - 1);
  if (gain) val *= gain[hh];
  if (do_rope) {
    float pr = __shfl_xor(val, 32, 64);
    int jj = lane & 31;
    float c = cosT[t * 32 + jj];
    float s = sinT[t * 32 + jj];
    val = (lane < 32) ? (val * c + pr * s) : (val * c - pr * s);
  }
  P[idx] = val;
}

// ---------------------------------------------------------------- causal attention, 16 queries/block
__global__ __launch_bounds__(256) void attn_k(const float* __restrict__ Q,
                                              const float* __restrict__ K,
                                              const float* __restrict__ V,
                                              float* __restrict__ O) {
  __shared__ float Qs[16][65];
  __shared__ float Ks[64][65];
  __shared__ float Vs[64][65];
  __shared__ float Ps[16][65];
  const int q0 = blockIdx.x * 16;
  const int bh = blockIdx.y;
  const int b = bh >> 4, hh = bh & 15;
  const int kvh = hh >> 2;
  const int tid = threadIdx.x;
  {
    int r = tid >> 4;
    int c = (tid & 15) * 4;
    const float* src = Q + ((size_t)(b * TT + q0 + r) * (HH * 64)) + hh * 64 + c;
    float4 v = *reinterpret_cast<const float4*>(src);
    Qs[r][c] = v.x; Qs[r][c + 1] = v.y; Qs[r][c + 2] = v.z; Qs[r][c + 3] = v.w;
  }
  const int q = tid >> 4;
  const int kb4 = (tid & 15) * 4;
  const int qt = q0 + q;
  float o0 = 0.f, o1 = 0.f, o2 = 0.f, o3 = 0.f;
  float denom = 0.f;
  for (int kc = 0; kc <= q0 + 15; kc += 64) {
#pragma unroll
    for (int i = 0; i < 4; ++i) {
      int rr = (tid >> 4) + i * 16;
      int cc = (tid & 15) * 4;
      size_t kidx = ((size_t)(b * TT + kc + rr) * (KVH * 64)) + kvh * 64 + cc;
      float4 kv = *reinterpret_cast<const float4*>(K + kidx);
      Ks[rr][cc] = kv.x; Ks[rr][cc + 1] = kv.y; Ks[rr][cc + 2] = kv.z; Ks[rr][cc + 3] = kv.w;
      float4 vv = *reinterpret_cast<const float4*>(V + kidx);
      Vs[rr][cc] = vv.x; Vs[rr][cc + 1] = vv.y; Vs[rr][cc + 2] = vv.z; Vs[rr][cc + 3] = vv.w;
    }
    __syncthreads();
    float psum = 0.f;
#pragma unroll
    for (int j = 0; j < 4; ++j) {
      int kk = kb4 + j;
      int kglob = kc + kk;
      float s = 0.f;
#pragma unroll
      for (int d = 0; d < 64; ++d) s += Qs[q][d] * Ks[kk][d];
      float pp = (kglob <= qt) ? expf(s) : 0.f;
      Ps[q][kk] = pp;
      psum += pp;
    }
#pragma unroll
    for (int m = 1; m < 16; m <<= 1) psum += __shfl_xor(psum, m, 64);
    denom += psum;
    __syncthreads();
#pragma unroll 8
    for (int kk = 0; kk < 64; ++kk) {
      float pp = Ps[q][kk];
      o0 += pp * Vs[kk][kb4 + 0];
      o1 += pp * Vs[kk][kb4 + 1];
      o2 += pp * Vs[kk][kb4 + 2];
      o3 += pp * Vs[kk][kb4 + 3];
    }
    __syncthreads();
  }
  float invd = 1.0f / denom;
  size_t oidx = ((size_t)(b * TT + qt) * (HH * 64)) + hh * 64 + kb4;
  float4 ov;
  ov.x = o0 * invd; ov.y = o1 * invd; ov.z = o2 * invd; ov.w = o3 * invd;
  *reinterpret_cast<float4*>(O + oidx) = ov;
}

// ---------------------------------------------------------------- causal depthwise conv (CK=4) + silu + split
__global__ __launch_bounds__(256) void conv_k(const float* __restrict__ X,
                                              const float* __restrict__ Wc,
                                              float* __restrict__ Qo,
                                              float* __restrict__ Ko,
                                              float* __restrict__ Vo) {
  int idx = blockIdx.x * 256 + threadIdx.x;   // B*T*3072 exact
  int c = idx % 3072;
  int rest = idx / 3072;
  int t = rest & (TT - 1);
  int b = rest >> 10;
  const float* w = Wc + c * 4;
  float acc = 0.f;
#pragma unroll
  for (int j = 0; j < 4; ++j) {
    int tt = t - 3 + j;
    if (tt >= 0) acc += w[j] * X[((size_t)(b * TT + tt)) * 3072 + c];
  }
  float y = acc / (1.f + expf(-acc));   // silu
  int which = c >> 10, cc = c & 1023;
  float* dst = (which == 0) ? Qo : ((which == 1) ? Ko : Vo);
  dst[((size_t)(b * TT + t)) * 1024 + cc] = y;
}

// ---------------------------------------------------------------- GDN scan: one wave per (b,h,v-column)
__global__ __launch_bounds__(256) void gdn_scan_k(const float* __restrict__ Qg,
                                                  const float* __restrict__ Kg,
                                                  const float* __restrict__ Vg,
                                                  const float* __restrict__ Al,
                                                  const float* __restrict__ Be,
                                                  float* __restrict__ Og) {
  const int bh = blockIdx.x >> 4;        // b*16+h
  const int vblk = blockIdx.x & 15;
  const int wid = threadIdx.x >> 6;
  const int lane = threadIdx.x & 63;
  const int v = vblk * 4 + wid;
  const int b = bh >> 4, hh = bh & 15;
  float S = 0.f;
  size_t p = (size_t)b * TT * 1024 + hh * 64;
  size_t ab = (size_t)b * TT * HH + hh;
  float kd = Kg[p + lane], qd = Qg[p + lane], vv = Vg[p + v];
  float a = Al[ab], bt = Be[ab];
  for (int t = 0; t < TT; ++t) {
    float kdn = 0.f, qdn = 0.f, vvn = 0.f, an = 0.f, btn = 0.f;
    if (t < TT - 1) {
      size_t pn = p + 1024;
      kdn = Kg[pn + lane]; qdn = Qg[pn + lane]; vvn = Vg[pn + v];
      an = Al[ab + HH]; btn = Be[ab + HH];
    }
    float ks = kd * S;
#pragma unroll
    for (int m = 1; m < 64; m <<= 1) ks += __shfl_xor(ks, m, 64);
    S = a * (S - bt * kd * ks) + kd * vv;
    float o = qd * S;
#pragma unroll
    for (int m = 1; m < 64; m <<= 1) o += __shfl_xor(o, m, 64);
    if (lane == 0) Og[p + v] = o;
    p += 1024; ab += HH;
    kd = kdn; qd = qdn; vv = vvn; a = an; bt = btn;
  }
}

// ---------------------------------------------------------------- rmsnorm over 64 * gate (in place)
__global__ __launch_bounds__(256) void rms64_mul_k(float* __restrict__ O,
                                                   const float* __restrict__ G) {
  int row = blockIdx.x * 4 + (threadIdx.x >> 6);
  int lane = threadIdx.x & 63;
  size_t idx = (size_t)row * 64 + lane;
  float val = O[idx];
  float ss = val * val;
#pragma unroll
  for (int m = 1; m < 64; m <<= 1) ss += __shfl_xor(ss, m, 64);
  float sc = rsqrtf(ss * (1.0f / 64.0f) + 1e-6f);
  O[idx] = val * sc * G[idx];
}

// ---------------------------------------------------------------- host-side launch
static inline void gemm(hipStream_t s, const float* A, const float* W, float* C,
                        int M, int N, int K, int ldC, int act, int res) {
  if ((N % 128 == 0) && (K % 32 == 0) && (M % 128 == 0)) {
    dim3 g(N / 128, M / 128);
    mfma_gemm_k<<<g, 256, 0, s>>>(A, W, C, M, N, K, ldC, act, res);
  } else {
    dim3 g((N + 63) / 64, (M + 63) / 64);
    sgemm_k<<<g, 256, 0, s>>>(A, W, C, M, N, K, ldC, act, res);
  }
}

extern "C" void kernel_launch(void* const* d_in, const int* in_sizes, int n_in,
                              void* d_out, int out_size, void* d_ws, size_t ws_size,
                              hipStream_t stream) {
  const int*   tokens = (const int*)d_in[0];
  const float* emb    = (const float*)d_in[1];
  const float* aw_q   = (const float*)d_in[2];
  const float* aw_k   = (const float*)d_in[3];
  const float* aw_v   = (const float*)d_in[4];
  const float* aw_o   = (const float*)d_in[5];
  const float* a_gain = (const float*)d_in[6];
  const float* a_m1   = (const float*)d_in[7];
  const float* a_m2   = (const float*)d_in[8];
  const float* g_wq   = (const float*)d_in[9];
  const float* g_wk   = (const float*)d_in[10];
  const float* g_wv   = (const float*)d_in[11];
  const float* g_wa   = (const float*)d_in[12];
  const float* g_wb   = (const float*)d_in[13];
  const float* g_wg   = (const float*)d_in[14];
  const float* g_wo   = (const float*)d_in[15];
  const float* g_conv = (const float*)d_in[16];
  const float* g_m1   = (const float*)d_in[17];
  const float* g_m2   = (const float*)d_in[18];

  const int M = BB * TT;  // 2048

  float* ws = (float*)d_ws;
  float* x    = ws;                  // 2097152
  float* h    = x + 2097152;         // 2097152
  float* qb   = h + 2097152;         // 2097152 (attn q)
  float* kb   = qb + 2097152;        // 524288  (attn k)
  float* vb   = kb + 524288;         // 524288  (attn v)
  float* qg   = vb + 524288;         // 2097152 (gdn q / attn o_flat)
  float* kg   = qg + 2097152;        // 2097152
  float* vg   = kg + 2097152;        // 2097152
  float* og   = vg + 2097152;        // 2097152
  float* gb   = og + 2097152;        // 2097152
  float* alp  = gb + 2097152;        // 32768
  float* bet  = alp + 32768;         // 32768
  float* cosT = bet + 32768;         // 32768
  float* sinT = cosT + 32768;        // 32768

  // big scratch lives in d_out (fully rewritten by the final logits GEMM)
  float* outF = (float*)d_out;
  float* mid  = outF;                // 8388608  (B*T*DFF)
  float* qkv  = outF + 8388608;      // 6291456  (B*T*3072)

  rope_tab_k<<<128, 256, 0, stream>>>(cosT, sinT);
  embed_k<<<M, 256, 0, stream>>>(tokens, emb, x);

  for (int i = 0; i < 2; ++i) {
    const float* wq = aw_q + (size_t)i * 1024 * 1024;
    const float* wk = aw_k + (size_t)i * 256 * 1024;
    const float* wv = aw_v + (size_t)i * 256 * 1024;
    const float* wo = aw_o + (size_t)i * 1024 * 1024;
    const float* gn = a_gain + (size_t)i * 16;
    const float* m1 = a_m1 + (size_t)i * 4096 * 1024;
    const float* m2 = a_m2 + (size_t)i * 1024 * 4096;
    const float* zq = g_wq + (size_t)i * 1024 * 1024;
    const float* zk = g_wk + (size_t)i * 1024 * 1024;
    const float* zv = g_wv + (size_t)i * 1024 * 1024;
    const float* za = g_wa + (size_t)i * 16 * 1024;
    const float* zb = g_wb + (size_t)i * 16 * 1024;
    const float* zg = g_wg + (size_t)i * 1024 * 1024;
    const float* zo = g_wo + (size_t)i * 1024 * 1024;
    const float* zc = g_conv + (size_t)i * 3072 * 4;
    const float* n1 = g_m1 + (size_t)i * 4096 * 1024;
    const float* n2 = g_m2 + (size_t)i * 1024 * 4096;

    // ---------------- attention block ----------------
    rmsnorm_k<<<M, 256, 0, stream>>>(x, h);
    gemm(stream, h, wq, qb, M, 1024, 1024, 1024, ACT_NONE, 0);
    gemm(stream, h, wk, kb, M, 256, 1024, 256, ACT_NONE, 0);
    gemm(stream, h, wv, vb, M, 256, 1024, 256, ACT_NONE, 0);
    l2n_rope_k<<<(M * HH) / 4, 256, 0, stream>>>(qb, HH, gn, cosT, sinT, 1);
    l2n_rope_k<<<(M * KVH) / 4, 256, 0, stream>>>(kb, KVH, nullptr, cosT, sinT, 1);
    attn_k<<<dim3(TT / 16, BB * HH), 256, 0, stream>>>(qb, kb, vb, qg);
    gemm(stream, qg, wo, x, M, 1024, 1024, 1024, ACT_NONE, 1);
    rmsnorm_k<<<M, 256, 0, stream>>>(x, h);
    gemm(stream, h, m1, mid, M, DFF, 1024, DFF, ACT_RELU2, 0);
    gemm(stream, mid, m2, x, M, 1024, DFF, 1024, ACT_NONE, 1);

    // ---------------- GDN block ----------------
    rmsnorm_k<<<M, 256, 0, stream>>>(x, h);
    gemm(stream, h, zq, qkv + 0,    M, 1024, 1024, 3072, ACT_NONE, 0);
    gemm(stream, h, zk, qkv + 1024, M, 1024, 1024, 3072, ACT_NONE, 0);
    gemm(stream, h, zv, qkv + 2048, M, 1024, 1024, 3072, ACT_NONE, 0);
    conv_k<<<(M * 3072) / 256, 256, 0, stream>>>(qkv, zc, qg, kg, vg);
    l2n_rope_k<<<(M * HH) / 4, 256, 0, stream>>>(qg, HH, nullptr, nullptr, nullptr, 0);
    l2n_rope_k<<<(M * HH) / 4, 256, 0, stream>>>(kg, HH, nullptr, nullptr, nullptr, 0);
    gemm(stream, h, za, alp, M, 16, 1024, 16, ACT_SIG, 0);
    gemm(stream, h, zb, bet, M, 16, 1024, 16, ACT_SIG, 0);
    gdn_scan_k<<<BB * HH * 16, 256, 0, stream>>>(qg, kg, vg, alp, bet, og);
    gemm(stream, h, zg, gb, M, 1024, 1024, 1024, ACT_SILU, 0);
    rms64_mul_k<<<(M * HH) / 4, 256, 0, stream>>>(og, gb);
    gemm(stream, og, zo, x, M, 1024, 1024, 1024, ACT_NONE, 1);
    rmsnorm_k<<<M, 256, 0, stream>>>(x, h);
    gemm(stream, h, n1, mid, M, DFF, 1024, DFF, ACT_RELU2, 0);
    gemm(stream, mid, n2, x, M, 1024, DFF, 1024, ACT_NONE, 1);
  }

  // ---------------- final logits ----------------
  rmsnorm_k<<<M, 256, 0, stream>>>(x, h);
  gemm(stream, h, emb, outF, M, VV, 1024, VV, ACT_NONE, 0);
}

// Round 3
// 4988.814 us; speedup vs baseline: 2.0665x; 1.0191x over previous
//
#include <hip/hip_runtime.h>
#include <hip/hip_bf16.h>
#include <math.h>

// ---------------------------------------------------------------- constants
#define BB 2
#define TT 1024
#define DD 1024
#define HH 16
#define KVH 4
#define HDIM 64
#define VV 32768
#define DFF 4096

#define ACT_NONE 0
#define ACT_RELU2 1
#define ACT_SILU 2
#define ACT_SIG 3

typedef __attribute__((ext_vector_type(8))) short short8v;
typedef __attribute__((ext_vector_type(4))) float f32x4;

__device__ inline ushort f2bf(float f) {
  uint u = __float_as_uint(f);
  uint r = u + 0x7FFFu + ((u >> 16) & 1u);
  return (ushort)(r >> 16);
}
__device__ inline uint pack2(float lo, float hi) {
  return (uint)f2bf(lo) | ((uint)f2bf(hi) << 16);
}

// ---------------------------------------------------------------- rope tables
__global__ __launch_bounds__(256) void rope_tab_k(float* __restrict__ cosT,
                                                  float* __restrict__ sinT) {
  int idx = blockIdx.x * 256 + threadIdx.x;   // T*32 = 32768 total
  int t = idx >> 5, j = idx & 31;
  float inv = 1.0f / powf(10000.0f, (float)(2 * j) * (1.0f / 64.0f));
  float fr = (float)t * inv;
  cosT[idx] = cosf(fr);
  sinT[idx] = sinf(fr);
}

// ---------------------------------------------------------------- embedding gather
__global__ __launch_bounds__(256) void embed_k(const int* __restrict__ tok,
                                               const float* __restrict__ emb,
                                               float* __restrict__ X) {
  int row = blockIdx.x;          // B*T rows
  int tid = threadIdx.x;
  int tk = tok[row];
  float4 v = *reinterpret_cast<const float4*>(emb + (size_t)tk * DD + tid * 4);
  *reinterpret_cast<float4*>(X + (size_t)row * DD + tid * 4) = v;
}

// ---------------------------------------------------------------- rmsnorm over D=1024
__global__ __launch_bounds__(256) void rmsnorm_k(const float* __restrict__ in,
                                                 float* __restrict__ out) {
  int row = blockIdx.x;
  int tid = threadIdx.x;
  const float* p = in + (size_t)row * DD;
  float4 v = *reinterpret_cast<const float4*>(p + tid * 4);
  float ss = v.x * v.x + v.y * v.y + v.z * v.z + v.w * v.w;
#pragma unroll
  for (int m = 1; m < 64; m <<= 1) ss += __shfl_xor(ss, m, 64);
  __shared__ float wsum[4];
  int wid = tid >> 6, lane = tid & 63;
  if (lane == 0) wsum[wid] = ss;
  __syncthreads();
  float tot = wsum[0] + wsum[1] + wsum[2] + wsum[3];
  float sc = rsqrtf(tot * (1.0f / 1024.0f) + 1e-6f);
  float4 o;
  o.x = v.x * sc; o.y = v.y * sc; o.z = v.z * sc; o.w = v.w * sc;
  *reinterpret_cast<float4*>(out + (size_t)row * DD + tid * 4) = o;
}

// ---------------------------------------------------------------- MFMA bf16 GEMM: C = [res +] act(A @ W^T)
__global__ __launch_bounds__(256) void mfma_gemm_k(const float* __restrict__ A,
                                                   const float* __restrict__ W,
                                                   float* __restrict__ C,
                                                   int M, int N, int K, int ldC,
                                                   int act, int res) {
  __shared__ ushort As[128 * 40];   // row stride 40 bf16 (80B) to spread banks
  __shared__ ushort Ws[128 * 40];
  const int bm = blockIdx.y * 128;
  const int bn = blockIdx.x * 128;
  const int tid = threadIdx.x;
  const int wave = tid >> 6, lane = tid & 63;
  const int wr = wave >> 1, wc = wave & 1;
  const int lr = lane & 15, lk = (lane >> 4) * 8;   // frag row-in-tile, k-base

  const int srow = tid >> 3;        // 0..31
  const int scol = (tid & 7) * 4;   // 0..28

  f32x4 acc[4][4] = {};

  for (int k0 = 0; k0 < K; k0 += 32) {
#pragma unroll
    for (int p = 0; p < 4; ++p) {
      int row = p * 32 + srow;
      float4 av = *reinterpret_cast<const float4*>(A + (size_t)(bm + row) * K + k0 + scol);
      uint2 aw; aw.x = pack2(av.x, av.y); aw.y = pack2(av.z, av.w);
      *reinterpret_cast<uint2*>(&As[row * 40 + scol]) = aw;
      float4 wv = *reinterpret_cast<const float4*>(W + (size_t)(bn + row) * K + k0 + scol);
      uint2 ww; ww.x = pack2(wv.x, wv.y); ww.y = pack2(wv.z, wv.w);
      *reinterpret_cast<uint2*>(&Ws[row * 40 + scol]) = ww;
    }
    __syncthreads();
    short8v av[4], bv[4];
#pragma unroll
    for (int m = 0; m < 4; ++m)
      av[m] = *reinterpret_cast<const short8v*>(&As[(wr * 64 + m * 16 + lr) * 40 + lk]);
#pragma unroll
    for (int n = 0; n < 4; ++n)
      bv[n] = *reinterpret_cast<const short8v*>(&Ws[(wc * 64 + n * 16 + lr) * 40 + lk]);
#pragma unroll
    for (int m = 0; m < 4; ++m)
#pragma unroll
      for (int n = 0; n < 4; ++n)
        acc[m][n] = __builtin_amdgcn_mfma_f32_16x16x32_bf16(av[m], bv[n], acc[m][n], 0, 0, 0);
    __syncthreads();
  }

  const int rj = (lane >> 4) * 4;
#pragma unroll
  for (int m = 0; m < 4; ++m) {
    int rowb = bm + wr * 64 + m * 16 + rj;
#pragma unroll
    for (int n = 0; n < 4; ++n) {
      int col = bn + wc * 64 + n * 16 + lr;
#pragma unroll
      for (int j = 0; j < 4; ++j) {
        float v = acc[m][n][j];
        if (act == ACT_RELU2) { v = fmaxf(v, 0.f); v = v * v; }
        else if (act == ACT_SILU) { v = v / (1.f + expf(-v)); }
        float* cp = C + (size_t)(rowb + j) * ldC + col;
        if (res) v += *cp;
        *cp = v;
      }
    }
  }
}

// ---------------------------------------------------------------- fp32 SGEMM (small N fallback)
__global__ __launch_bounds__(256) void sgemm_k(const float* __restrict__ A,
                                               const float* __restrict__ W,
                                               float* __restrict__ C,
                                               int M, int N, int K, int ldC,
                                               int act, int res) {
  __shared__ float Asm[16][65];
  __shared__ float Wsm[16][65];
  const int bm = blockIdx.y * 64;
  const int bn = blockIdx.x * 64;
  const int tid = threadIdx.x;
  const int tx = tid & 15, ty = tid >> 4;
  const int lr = tid >> 2;          // 0..63
  const int lc = (tid & 3) * 4;     // 0,4,8,12
  float acc[4][4] = {{0.f}};
  for (int k0 = 0; k0 < K; k0 += 16) {
    int arow = bm + lr;
    float4 av = make_float4(0.f, 0.f, 0.f, 0.f);
    if (arow < M) av = *reinterpret_cast<const float4*>(A + (size_t)arow * K + k0 + lc);
    Asm[lc + 0][lr] = av.x; Asm[lc + 1][lr] = av.y; Asm[lc + 2][lr] = av.z; Asm[lc + 3][lr] = av.w;
    int wrow = bn + lr;
    float4 wv = make_float4(0.f, 0.f, 0.f, 0.f);
    if (wrow < N) wv = *reinterpret_cast<const float4*>(W + (size_t)wrow * K + k0 + lc);
    Wsm[lc + 0][lr] = wv.x; Wsm[lc + 1][lr] = wv.y; Wsm[lc + 2][lr] = wv.z; Wsm[lc + 3][lr] = wv.w;
    __syncthreads();
#pragma unroll
    for (int kk = 0; kk < 16; ++kk) {
      float a[4], b[4];
#pragma unroll
      for (int i = 0; i < 4; ++i) a[i] = Asm[kk][ty * 4 + i];
#pragma unroll
      for (int j = 0; j < 4; ++j) b[j] = Wsm[kk][tx * 4 + j];
#pragma unroll
      for (int i = 0; i < 4; ++i)
#pragma unroll
        for (int j = 0; j < 4; ++j) acc[i][j] += a[i] * b[j];
    }
    __syncthreads();
  }
#pragma unroll
  for (int i = 0; i < 4; ++i) {
    int row = bm + ty * 4 + i;
    if (row >= M) continue;
#pragma unroll
    for (int j = 0; j < 4; ++j) {
      int col = bn + tx * 4 + j;
      if (col >= N) continue;
      float v = acc[i][j];
      if (act == ACT_RELU2) { v = fmaxf(v, 0.f); v = v * v; }
      else if (act == ACT_SILU) { v = v / (1.f + expf(-v)); }
      else if (act == ACT_SIG) { v = 1.f / (1.f + expf(-v)); }
      float* cp = C + (size_t)row * ldC + col;
      if (res) v += *cp;
      *cp = v;
    }
  }
}

// ---------------------------------------------------------------- l2norm (+gain) (+rope) on rows of 64
__global__ __launch_bounds__(256) void l2n_rope_k(float* __restrict__ P, int NH,
                                                  const float* __restrict__ gain,
                                                  const float* __restrict__ cosT,
                                                  const float* __restrict__ sinT,
                                                  int do_rope) {
  int row = blockIdx.x * 4 + (threadIdx.x >> 6);
  int lane = threadIdx.x & 63;
  size_t idx = (size_t)row * 64 + lane;
  float val = P[idx];
  float ss = val * val;
#pragma unroll
  for (int m = 1; m < 64; m <<= 1) ss += __shfl_xor(ss, m, 64);
  val = val / fmaxf(sqrtf(ss), 1e-6f);
  int hh = row % NH;
  int t = (row / NH) & (TT - 1);
  if (gain) val *= gain[hh];
  if (do_rope) {
    float pr = __shfl_xor(val, 32, 64);
    int jj = lane & 31;
    float c = cosT[t * 32 + jj];
    float s = sinT[t * 32 + jj];
    val = (lane < 32) ? (val * c + pr * s) : (val * c - pr * s);
  }
  P[idx] = val;
}

// ---------------------------------------------------------------- causal attention, 16 queries/block
__global__ __launch_bounds__(256) void attn_k(const float* __restrict__ Q,
                                              const float* __restrict__ K,
                                              const float* __restrict__ V,
                                              float* __restrict__ O) {
  __shared__ float Qs[16][65];
  __shared__ float Ks[64][65];
  __shared__ float Vs[64][65];
  __shared__ float Ps[16][65];
  const int q0 = blockIdx.x * 16;
  const int bh = blockIdx.y;
  const int b = bh >> 4, hh = bh & 15;
  const int kvh = hh >> 2;
  const int tid = threadIdx.x;
  {
    int r = tid >> 4;
    int c = (tid & 15) * 4;
    const float* src = Q + ((size_t)(b * TT + q0 + r) * (HH * 64)) + hh * 64 + c;
    float4 v = *reinterpret_cast<const float4*>(src);
    Qs[r][c] = v.x; Qs[r][c + 1] = v.y; Qs[r][c + 2] = v.z; Qs[r][c + 3] = v.w;
  }
  const int q = tid >> 4;
  const int kb4 = (tid & 15) * 4;
  const int qt = q0 + q;
  float o0 = 0.f, o1 = 0.f, o2 = 0.f, o3 = 0.f;
  float denom = 0.f;
  for (int kc = 0; kc <= q0 + 15; kc += 64) {
#pragma unroll
    for (int i = 0; i < 4; ++i) {
      int rr = (tid >> 4) + i * 16;
      int cc = (tid & 15) * 4;
      size_t kidx = ((size_t)(b * TT + kc + rr) * (KVH * 64)) + kvh * 64 + cc;
      float4 kv = *reinterpret_cast<const float4*>(K + kidx);
      Ks[rr][cc] = kv.x; Ks[rr][cc + 1] = kv.y; Ks[rr][cc + 2] = kv.z; Ks[rr][cc + 3] = kv.w;
      float4 vv = *reinterpret_cast<const float4*>(V + kidx);
      Vs[rr][cc] = vv.x; Vs[rr][cc + 1] = vv.y; Vs[rr][cc + 2] = vv.z; Vs[rr][cc + 3] = vv.w;
    }
    __syncthreads();
    float psum = 0.f;
#pragma unroll
    for (int j = 0; j < 4; ++j) {
      int kk = kb4 + j;
      int kglob = kc + kk;
      float s = 0.f;
#pragma unroll
      for (int d = 0; d < 64; ++d) s += Qs[q][d] * Ks[kk][d];
      float pp = (kglob <= qt) ? expf(s) : 0.f;
      Ps[q][kk] = pp;
      psum += pp;
    }
#pragma unroll
    for (int m = 1; m < 16; m <<= 1) psum += __shfl_xor(psum, m, 64);
    denom += psum;
    __syncthreads();
#pragma unroll 8
    for (int kk = 0; kk < 64; ++kk) {
      float pp = Ps[q][kk];
      o0 += pp * Vs[kk][kb4 + 0];
      o1 += pp * Vs[kk][kb4 + 1];
      o2 += pp * Vs[kk][kb4 + 2];
      o3 += pp * Vs[kk][kb4 + 3];
    }
    __syncthreads();
  }
  float invd = 1.0f / denom;
  size_t oidx = ((size_t)(b * TT + qt) * (HH * 64)) + hh * 64 + kb4;
  float4 ov;
  ov.x = o0 * invd; ov.y = o1 * invd; ov.z = o2 * invd; ov.w = o3 * invd;
  *reinterpret_cast<float4*>(O + oidx) = ov;
}

// ---------------------------------------------------------------- causal depthwise conv (CK=4) + silu + split
__global__ __launch_bounds__(256) void conv_k(const float* __restrict__ X,
                                              const float* __restrict__ Wc,
                                              float* __restrict__ Qo,
                                              float* __restrict__ Ko,
                                              float* __restrict__ Vo) {
  int idx = blockIdx.x * 256 + threadIdx.x;   // B*T*3072 exact
  int c = idx % 3072;
  int rest = idx / 3072;
  int t = rest & (TT - 1);
  int b = rest >> 10;
  const float* w = Wc + c * 4;
  float acc = 0.f;
#pragma unroll
  for (int j = 0; j < 4; ++j) {
    int tt = t - 3 + j;
    if (tt >= 0) acc += w[j] * X[((size_t)(b * TT + tt)) * 3072 + c];
  }
  float y = acc / (1.f + expf(-acc));   // silu
  int which = c >> 10, cc = c & 1023;
  float* dst = (which == 0) ? Qo : ((which == 1) ? Ko : Vo);
  dst[((size_t)(b * TT + t)) * 1024 + cc] = y;
}

// ---------------------------------------------------------------- GDN scan v2
// One block (64 threads) per (b,h,vgroup). Lane = vloc*4 + dgrp:
// lane owns S[dgrp*16 .. +16, v] in registers; reduction over d = 16 local FMA
// + 2 shfl_xor within the 4-lane group. k/q/v/a/b prefetched one step ahead.
__global__ __launch_bounds__(64) void gdn_scan_k(const float* __restrict__ Qg,
                                                 const float* __restrict__ Kg,
                                                 const float* __restrict__ Vg,
                                                 const float* __restrict__ Al,
                                                 const float* __restrict__ Be,
                                                 float* __restrict__ Og) {
  const int bh = blockIdx.x >> 2;        // b*16+h
  const int vgrp = blockIdx.x & 3;
  const int lane = threadIdx.x;
  const int vloc = lane >> 2;            // 0..15
  const int dgrp = lane & 3;             // 0..3
  const int v = vgrp * 16 + vloc;
  const int b = bh >> 4, hh = bh & 15;
  const int d0 = dgrp * 16;

  float S[16];
#pragma unroll
  for (int i = 0; i < 16; ++i) S[i] = 0.f;

  size_t p = (size_t)b * TT * 1024 + hh * 64;
  size_t ab = (size_t)b * TT * HH + hh;

  float kk[16], qq[16], kn[16], qn[16];
  float vv, a, bt;
  {
    const float* kp = Kg + p + d0;
    const float* qp = Qg + p + d0;
#pragma unroll
    for (int i = 0; i < 4; ++i) {
      float4 kv = *reinterpret_cast<const float4*>(kp + i * 4);
      kk[4 * i] = kv.x; kk[4 * i + 1] = kv.y; kk[4 * i + 2] = kv.z; kk[4 * i + 3] = kv.w;
      float4 qv = *reinterpret_cast<const float4*>(qp + i * 4);
      qq[4 * i] = qv.x; qq[4 * i + 1] = qv.y; qq[4 * i + 2] = qv.z; qq[4 * i + 3] = qv.w;
    }
    vv = Vg[p + v]; a = Al[ab]; bt = Be[ab];
  }

  for (int t = 0; t < TT; ++t) {
    float vvn = 0.f, an = 0.f, btn = 0.f;
    if (t < TT - 1) {
      const float* kp = Kg + p + 1024 + d0;
      const float* qp = Qg + p + 1024 + d0;
#pragma unroll
      for (int i = 0; i < 4; ++i) {
        float4 kv = *reinterpret_cast<const float4*>(kp + i * 4);
        kn[4 * i] = kv.x; kn[4 * i + 1] = kv.y; kn[4 * i + 2] = kv.z; kn[4 * i + 3] = kv.w;
        float4 qv = *reinterpret_cast<const float4*>(qp + i * 4);
        qn[4 * i] = qv.x; qn[4 * i + 1] = qv.y; qn[4 * i + 2] = qv.z; qn[4 * i + 3] = qv.w;
      }
      vvn = Vg[p + 1024 + v]; an = Al[ab + HH]; btn = Be[ab + HH];
    }
    // kS partial dot (4 accumulators) + 4-lane reduce
    float t0 = 0.f, t1 = 0.f, t2 = 0.f, t3 = 0.f;
#pragma unroll
    for (int i = 0; i < 16; i += 4) {
      t0 += kk[i] * S[i];
      t1 += kk[i + 1] * S[i + 1];
      t2 += kk[i + 2] * S[i + 2];
      t3 += kk[i + 3] * S[i + 3];
    }
    float ks = (t0 + t1) + (t2 + t3);
    ks += __shfl_xor(ks, 1, 64);
    ks += __shfl_xor(ks, 2, 64);
    float c = vv - a * bt * ks;
    // state update fused with out-dot
    float o0 = 0.f, o1 = 0.f, o2 = 0.f, o3 = 0.f;
#pragma unroll
    for (int i = 0; i < 16; i += 4) {
      S[i] = a * S[i] + c * kk[i];             o0 += qq[i] * S[i];
      S[i + 1] = a * S[i + 1] + c * kk[i + 1]; o1 += qq[i + 1] * S[i + 1];
      S[i + 2] = a * S[i + 2] + c * kk[i + 2]; o2 += qq[i + 2] * S[i + 2];
      S[i + 3] = a * S[i + 3] + c * kk[i + 3]; o3 += qq[i + 3] * S[i + 3];
    }
    float o = (o0 + o1) + (o2 + o3);
    o += __shfl_xor(o, 1, 64);
    o += __shfl_xor(o, 2, 64);
    if (dgrp == 0) Og[p + v] = o;
    p += 1024; ab += HH;
#pragma unroll
    for (int i = 0; i < 16; ++i) { kk[i] = kn[i]; qq[i] = qn[i]; }
    vv = vvn; a = an; bt = btn;
  }
}

// ---------------------------------------------------------------- rmsnorm over 64 * gate (in place)
__global__ __launch_bounds__(256) void rms64_mul_k(float* __restrict__ O,
                                                   const float* __restrict__ G) {
  int row = blockIdx.x * 4 + (threadIdx.x >> 6);
  int lane = threadIdx.x & 63;
  size_t idx = (size_t)row * 64 + lane;
  float val = O[idx];
  float ss = val * val;
#pragma unroll
  for (int m = 1; m < 64; m <<= 1) ss += __shfl_xor(ss, m, 64);
  float sc = rsqrtf(ss * (1.0f / 64.0f) + 1e-6f);
  O[idx] = val * sc * G[idx];
}

// ---------------------------------------------------------------- host-side launch
static inline void gemm(hipStream_t s, const float* A, const float* W, float* C,
                        int M, int N, int K, int ldC, int act, int res) {
  if ((N % 128 == 0) && (K % 32 == 0) && (M % 128 == 0)) {
    dim3 g(N / 128, M / 128);
    mfma_gemm_k<<<g, 256, 0, s>>>(A, W, C, M, N, K, ldC, act, res);
  } else {
    dim3 g((N + 63) / 64, (M + 63) / 64);
    sgemm_k<<<g, 256, 0, s>>>(A, W, C, M, N, K, ldC, act, res);
  }
}

extern "C" void kernel_launch(void* const* d_in, const int* in_sizes, int n_in,
                              void* d_out, int out_size, void* d_ws, size_t ws_size,
                              hipStream_t stream) {
  const int*   tokens = (const int*)d_in[0];
  const float* emb    = (const float*)d_in[1];
  const float* aw_q   = (const float*)d_in[2];
  const float* aw_k   = (const float*)d_in[3];
  const float* aw_v   = (const float*)d_in[4];
  const float* aw_o   = (const float*)d_in[5];
  const float* a_gain = (const float*)d_in[6];
  const float* a_m1   = (const float*)d_in[7];
  const float* a_m2   = (const float*)d_in[8];
  const float* g_wq   = (const float*)d_in[9];
  const float* g_wk   = (const float*)d_in[10];
  const float* g_wv   = (const float*)d_in[11];
  const float* g_wa   = (const float*)d_in[12];
  const float* g_wb   = (const float*)d_in[13];
  const float* g_wg   = (const float*)d_in[14];
  const float* g_wo   = (const float*)d_in[15];
  const float* g_conv = (const float*)d_in[16];
  const float* g_m1   = (const float*)d_in[17];
  const float* g_m2   = (const float*)d_in[18];

  const int M = BB * TT;  // 2048

  float* ws = (float*)d_ws;
  float* x    = ws;                  // 2097152
  float* h    = x + 2097152;         // 2097152
  float* qb   = h + 2097152;         // 2097152 (attn q)
  float* kb   = qb + 2097152;        // 524288  (attn k)
  float* vb   = kb + 524288;         // 524288  (attn v)
  float* qg   = vb + 524288;         // 2097152 (gdn q / attn o_flat)
  float* kg   = qg + 2097152;        // 2097152
  float* vg   = kg + 2097152;        // 2097152
  float* og   = vg + 2097152;        // 2097152
  float* gb   = og + 2097152;        // 2097152
  float* alp  = gb + 2097152;        // 32768
  float* bet  = alp + 32768;         // 32768
  float* cosT = bet + 32768;         // 32768
  float* sinT = cosT + 32768;        // 32768

  // big scratch lives in d_out (fully rewritten by the final logits GEMM)
  float* outF = (float*)d_out;
  float* mid  = outF;                // 8388608  (B*T*DFF)
  float* qkv  = outF + 8388608;      // 6291456  (B*T*3072)

  rope_tab_k<<<128, 256, 0, stream>>>(cosT, sinT);
  embed_k<<<M, 256, 0, stream>>>(tokens, emb, x);

  for (int i = 0; i < 2; ++i) {
    const float* wq = aw_q + (size_t)i * 1024 * 1024;
    const float* wk = aw_k + (size_t)i * 256 * 1024;
    const float* wv = aw_v + (size_t)i * 256 * 1024;
    const float* wo = aw_o + (size_t)i * 1024 * 1024;
    const float* gn = a_gain + (size_t)i * 16;
    const float* m1 = a_m1 + (size_t)i * 4096 * 1024;
    const float* m2 = a_m2 + (size_t)i * 1024 * 4096;
    const float* zq = g_wq + (size_t)i * 1024 * 1024;
    const float* zk = g_wk + (size_t)i * 1024 * 1024;
    const float* zv = g_wv + (size_t)i * 1024 * 1024;
    const float* za = g_wa + (size_t)i * 16 * 1024;
    const float* zb = g_wb + (size_t)i * 16 * 1024;
    const float* zg = g_wg + (size_t)i * 1024 * 1024;
    const float* zo = g_wo + (size_t)i * 1024 * 1024;
    const float* zc = g_conv + (size_t)i * 3072 * 4;
    const float* n1 = g_m1 + (size_t)i * 4096 * 1024;
    const float* n2 = g_m2 + (size_t)i * 1024 * 4096;

    // ---------------- attention block ----------------
    rmsnorm_k<<<M, 256, 0, stream>>>(x, h);
    gemm(stream, h, wq, qb, M, 1024, 1024, 1024, ACT_NONE, 0);
    gemm(stream, h, wk, kb, M, 256, 1024, 256, ACT_NONE, 0);
    gemm(stream, h, wv, vb, M, 256, 1024, 256, ACT_NONE, 0);
    l2n_rope_k<<<(M * HH) / 4, 256, 0, stream>>>(qb, HH, gn, cosT, sinT, 1);
    l2n_rope_k<<<(M * KVH) / 4, 256, 0, stream>>>(kb, KVH, nullptr, cosT, sinT, 1);
    attn_k<<<dim3(TT / 16, BB * HH), 256, 0, stream>>>(qb, kb, vb, qg);
    gemm(stream, qg, wo, x, M, 1024, 1024, 1024, ACT_NONE, 1);
    rmsnorm_k<<<M, 256, 0, stream>>>(x, h);
    gemm(stream, h, m1, mid, M, DFF, 1024, DFF, ACT_RELU2, 0);
    gemm(stream, mid, m2, x, M, 1024, DFF, 1024, ACT_NONE, 1);

    // ---------------- GDN block ----------------
    rmsnorm_k<<<M, 256, 0, stream>>>(x, h);
    gemm(stream, h, zq, qkv + 0,    M, 1024, 1024, 3072, ACT_NONE, 0);
    gemm(stream, h, zk, qkv + 1024, M, 1024, 1024, 3072, ACT_NONE, 0);
    gemm(stream, h, zv, qkv + 2048, M, 1024, 1024, 3072, ACT_NONE, 0);
    conv_k<<<(M * 3072) / 256, 256, 0, stream>>>(qkv, zc, qg, kg, vg);
    l2n_rope_k<<<(M * HH) / 4, 256, 0, stream>>>(qg, HH, nullptr, nullptr, nullptr, 0);
    l2n_rope_k<<<(M * HH) / 4, 256, 0, stream>>>(kg, HH, nullptr, nullptr, nullptr, 0);
    gemm(stream, h, za, alp, M, 16, 1024, 16, ACT_SIG, 0);
    gemm(stream, h, zb, bet, M, 16, 1024, 16, ACT_SIG, 0);
    gdn_scan_k<<<BB * HH * 4, 64, 0, stream>>>(qg, kg, vg, alp, bet, og);
    gemm(stream, h, zg, gb, M, 1024, 1024, 1024, ACT_SILU, 0);
    rms64_mul_k<<<(M * HH) / 4, 256, 0, stream>>>(og, gb);
    gemm(stream, og, zo, x, M, 1024, 1024, 1024, ACT_NONE, 1);
    rmsnorm_k<<<M, 256, 0, stream>>>(x, h);
    gemm(stream, h, n1, mid, M, DFF, 1024, DFF, ACT_RELU2, 0);
    gemm(stream, mid, n2, x, M, 1024, DFF, 1024, ACT_NONE, 1);
  }

  // ---------------- final logits ----------------
  rmsnorm_k<<<M, 256, 0, stream>>>(x, h);
  gemm(stream, h, emb, outF, M, VV, 1024, VV, ACT_NONE, 0);
}

// Round 4
// 4635.583 us; speedup vs baseline: 2.2240x; 1.0762x over previous
//
#include <hip/hip_runtime.h>
#include <hip/hip_bf16.h>
#include <math.h>

// ---------------------------------------------------------------- constants
#define BB 2
#define TT 1024
#define DD 1024
#define HH 16
#define KVH 4
#define HDIM 64
#define VV 32768
#define DFF 4096

#define ACT_NONE 0
#define ACT_RELU2 1
#define ACT_SILU 2
#define ACT_SIG 3

typedef __attribute__((ext_vector_type(8))) short short8v;
typedef __attribute__((ext_vector_type(4))) float f32x4;

__device__ inline ushort f2bf(float f) {
  uint u = __float_as_uint(f);
  uint r = u + 0x7FFFu + ((u >> 16) & 1u);
  return (ushort)(r >> 16);
}
__device__ inline uint pack2(float lo, float hi) {
  return (uint)f2bf(lo) | ((uint)f2bf(hi) << 16);
}

// 4-lane (quad) sum via DPP quad_perm: xor1 (0xB1) then xor2 (0x4E). VALU-speed.
__device__ inline float qadd4(float x) {
  float y = __int_as_float(__builtin_amdgcn_update_dpp(
      0, __float_as_int(x), 0xB1, 0xF, 0xF, true));
  x += y;
  float z = __int_as_float(__builtin_amdgcn_update_dpp(
      0, __float_as_int(x), 0x4E, 0xF, 0xF, true));
  return x + z;
}

// ---------------------------------------------------------------- rope tables
__global__ __launch_bounds__(256) void rope_tab_k(float* __restrict__ cosT,
                                                  float* __restrict__ sinT) {
  int idx = blockIdx.x * 256 + threadIdx.x;   // T*32 = 32768 total
  int t = idx >> 5, j = idx & 31;
  float inv = 1.0f / powf(10000.0f, (float)(2 * j) * (1.0f / 64.0f));
  float fr = (float)t * inv;
  cosT[idx] = cosf(fr);
  sinT[idx] = sinf(fr);
}

// ---------------------------------------------------------------- embedding gather
__global__ __launch_bounds__(256) void embed_k(const int* __restrict__ tok,
                                               const float* __restrict__ emb,
                                               float* __restrict__ X) {
  int row = blockIdx.x;          // B*T rows
  int tid = threadIdx.x;
  int tk = tok[row];
  float4 v = *reinterpret_cast<const float4*>(emb + (size_t)tk * DD + tid * 4);
  *reinterpret_cast<float4*>(X + (size_t)row * DD + tid * 4) = v;
}

// ---------------------------------------------------------------- rmsnorm over D=1024
__global__ __launch_bounds__(256) void rmsnorm_k(const float* __restrict__ in,
                                                 float* __restrict__ out) {
  int row = blockIdx.x;
  int tid = threadIdx.x;
  const float* p = in + (size_t)row * DD;
  float4 v = *reinterpret_cast<const float4*>(p + tid * 4);
  float ss = v.x * v.x + v.y * v.y + v.z * v.z + v.w * v.w;
#pragma unroll
  for (int m = 1; m < 64; m <<= 1) ss += __shfl_xor(ss, m, 64);
  __shared__ float wsum[4];
  int wid = tid >> 6, lane = tid & 63;
  if (lane == 0) wsum[wid] = ss;
  __syncthreads();
  float tot = wsum[0] + wsum[1] + wsum[2] + wsum[3];
  float sc = rsqrtf(tot * (1.0f / 1024.0f) + 1e-6f);
  float4 o;
  o.x = v.x * sc; o.y = v.y * sc; o.z = v.z * sc; o.w = v.w * sc;
  *reinterpret_cast<float4*>(out + (size_t)row * DD + tid * 4) = o;
}

// ---------------------------------------------------------------- MFMA bf16 GEMM: C = [res +] act(A @ W^T)
__global__ __launch_bounds__(256) void mfma_gemm_k(const float* __restrict__ A,
                                                   const float* __restrict__ W,
                                                   float* __restrict__ C,
                                                   int M, int N, int K, int ldC,
                                                   int act, int res) {
  __shared__ ushort As[128 * 40];   // row stride 40 bf16 (80B) to spread banks
  __shared__ ushort Ws[128 * 40];
  const int bm = blockIdx.y * 128;
  const int bn = blockIdx.x * 128;
  const int tid = threadIdx.x;
  const int wave = tid >> 6, lane = tid & 63;
  const int wr = wave >> 1, wc = wave & 1;
  const int lr = lane & 15, lk = (lane >> 4) * 8;   // frag row-in-tile, k-base

  const int srow = tid >> 3;        // 0..31
  const int scol = (tid & 7) * 4;   // 0..28

  f32x4 acc[4][4] = {};

  for (int k0 = 0; k0 < K; k0 += 32) {
#pragma unroll
    for (int p = 0; p < 4; ++p) {
      int row = p * 32 + srow;
      float4 av = *reinterpret_cast<const float4*>(A + (size_t)(bm + row) * K + k0 + scol);
      uint2 aw; aw.x = pack2(av.x, av.y); aw.y = pack2(av.z, av.w);
      *reinterpret_cast<uint2*>(&As[row * 40 + scol]) = aw;
      float4 wv = *reinterpret_cast<const float4*>(W + (size_t)(bn + row) * K + k0 + scol);
      uint2 ww; ww.x = pack2(wv.x, wv.y); ww.y = pack2(wv.z, wv.w);
      *reinterpret_cast<uint2*>(&Ws[row * 40 + scol]) = ww;
    }
    __syncthreads();
    short8v av[4], bv[4];
#pragma unroll
    for (int m = 0; m < 4; ++m)
      av[m] = *reinterpret_cast<const short8v*>(&As[(wr * 64 + m * 16 + lr) * 40 + lk]);
#pragma unroll
    for (int n = 0; n < 4; ++n)
      bv[n] = *reinterpret_cast<const short8v*>(&Ws[(wc * 64 + n * 16 + lr) * 40 + lk]);
#pragma unroll
    for (int m = 0; m < 4; ++m)
#pragma unroll
      for (int n = 0; n < 4; ++n)
        acc[m][n] = __builtin_amdgcn_mfma_f32_16x16x32_bf16(av[m], bv[n], acc[m][n], 0, 0, 0);
    __syncthreads();
  }

  const int rj = (lane >> 4) * 4;
#pragma unroll
  for (int m = 0; m < 4; ++m) {
    int rowb = bm + wr * 64 + m * 16 + rj;
#pragma unroll
    for (int n = 0; n < 4; ++n) {
      int col = bn + wc * 64 + n * 16 + lr;
#pragma unroll
      for (int j = 0; j < 4; ++j) {
        float v = acc[m][n][j];
        if (act == ACT_RELU2) { v = fmaxf(v, 0.f); v = v * v; }
        else if (act == ACT_SILU) { v = v / (1.f + expf(-v)); }
        float* cp = C + (size_t)(rowb + j) * ldC + col;
        if (res) v += *cp;
        *cp = v;
      }
    }
  }
}

// ---------------------------------------------------------------- fp32 SGEMM (small N fallback)
__global__ __launch_bounds__(256) void sgemm_k(const float* __restrict__ A,
                                               const float* __restrict__ W,
                                               float* __restrict__ C,
                                               int M, int N, int K, int ldC,
                                               int act, int res) {
  __shared__ float Asm[16][65];
  __shared__ float Wsm[16][65];
  const int bm = blockIdx.y * 64;
  const int bn = blockIdx.x * 64;
  const int tid = threadIdx.x;
  const int tx = tid & 15, ty = tid >> 4;
  const int lr = tid >> 2;          // 0..63
  const int lc = (tid & 3) * 4;     // 0,4,8,12
  float acc[4][4] = {{0.f}};
  for (int k0 = 0; k0 < K; k0 += 16) {
    int arow = bm + lr;
    float4 av = make_float4(0.f, 0.f, 0.f, 0.f);
    if (arow < M) av = *reinterpret_cast<const float4*>(A + (size_t)arow * K + k0 + lc);
    Asm[lc + 0][lr] = av.x; Asm[lc + 1][lr] = av.y; Asm[lc + 2][lr] = av.z; Asm[lc + 3][lr] = av.w;
    int wrow = bn + lr;
    float4 wv = make_float4(0.f, 0.f, 0.f, 0.f);
    if (wrow < N) wv = *reinterpret_cast<const float4*>(W + (size_t)wrow * K + k0 + lc);
    Wsm[lc + 0][lr] = wv.x; Wsm[lc + 1][lr] = wv.y; Wsm[lc + 2][lr] = wv.z; Wsm[lc + 3][lr] = wv.w;
    __syncthreads();
#pragma unroll
    for (int kk = 0; kk < 16; ++kk) {
      float a[4], b[4];
#pragma unroll
      for (int i = 0; i < 4; ++i) a[i] = Asm[kk][ty * 4 + i];
#pragma unroll
      for (int j = 0; j < 4; ++j) b[j] = Wsm[kk][tx * 4 + j];
#pragma unroll
      for (int i = 0; i < 4; ++i)
#pragma unroll
        for (int j = 0; j < 4; ++j) acc[i][j] += a[i] * b[j];
    }
    __syncthreads();
  }
#pragma unroll
  for (int i = 0; i < 4; ++i) {
    int row = bm + ty * 4 + i;
    if (row >= M) continue;
#pragma unroll
    for (int j = 0; j < 4; ++j) {
      int col = bn + tx * 4 + j;
      if (col >= N) continue;
      float v = acc[i][j];
      if (act == ACT_RELU2) { v = fmaxf(v, 0.f); v = v * v; }
      else if (act == ACT_SILU) { v = v / (1.f + expf(-v)); }
      else if (act == ACT_SIG) { v = 1.f / (1.f + expf(-v)); }
      float* cp = C + (size_t)row * ldC + col;
      if (res) v += *cp;
      *cp = v;
    }
  }
}

// ---------------------------------------------------------------- l2norm (+gain) (+rope) on rows of 64
__global__ __launch_bounds__(256) void l2n_rope_k(float* __restrict__ P, int NH,
                                                  const float* __restrict__ gain,
                                                  const float* __restrict__ cosT,
                                                  const float* __restrict__ sinT,
                                                  int do_rope) {
  int row = blockIdx.x * 4 + (threadIdx.x >> 6);
  int lane = threadIdx.x & 63;
  size_t idx = (size_t)row * 64 + lane;
  float val = P[idx];
  float ss = val * val;
#pragma unroll
  for (int m = 1; m < 64; m <<= 1) ss += __shfl_xor(ss, m, 64);
  val = val / fmaxf(sqrtf(ss), 1e-6f);
  int hh = row % NH;
  int t = (row / NH) & (TT - 1);
  if (gain) val *= gain[hh];
  if (do_rope) {
    float pr = __shfl_xor(val, 32, 64);
    int jj = lane & 31;
    float c = cosT[t * 32 + jj];
    float s = sinT[t * 32 + jj];
    val = (lane < 32) ? (val * c + pr * s) : (val * c - pr * s);
  }
  P[idx] = val;
}

// ---------------------------------------------------------------- causal attention, 16 queries/block
__global__ __launch_bounds__(256) void attn_k(const float* __restrict__ Q,
                                              const float* __restrict__ K,
                                              const float* __restrict__ V,
                                              float* __restrict__ O) {
  __shared__ float Qs[16][65];
  __shared__ float Ks[64][65];
  __shared__ float Vs[64][65];
  __shared__ float Ps[16][65];
  const int q0 = blockIdx.x * 16;
  const int bh = blockIdx.y;
  const int b = bh >> 4, hh = bh & 15;
  const int kvh = hh >> 2;
  const int tid = threadIdx.x;
  {
    int r = tid >> 4;
    int c = (tid & 15) * 4;
    const float* src = Q + ((size_t)(b * TT + q0 + r) * (HH * 64)) + hh * 64 + c;
    float4 v = *reinterpret_cast<const float4*>(src);
    Qs[r][c] = v.x; Qs[r][c + 1] = v.y; Qs[r][c + 2] = v.z; Qs[r][c + 3] = v.w;
  }
  const int q = tid >> 4;
  const int kb4 = (tid & 15) * 4;
  const int qt = q0 + q;
  float o0 = 0.f, o1 = 0.f, o2 = 0.f, o3 = 0.f;
  float denom = 0.f;
  for (int kc = 0; kc <= q0 + 15; kc += 64) {
#pragma unroll
    for (int i = 0; i < 4; ++i) {
      int rr = (tid >> 4) + i * 16;
      int cc = (tid & 15) * 4;
      size_t kidx = ((size_t)(b * TT + kc + rr) * (KVH * 64)) + kvh * 64 + cc;
      float4 kv = *reinterpret_cast<const float4*>(K + kidx);
      Ks[rr][cc] = kv.x; Ks[rr][cc + 1] = kv.y; Ks[rr][cc + 2] = kv.z; Ks[rr][cc + 3] = kv.w;
      float4 vv = *reinterpret_cast<const float4*>(V + kidx);
      Vs[rr][cc] = vv.x; Vs[rr][cc + 1] = vv.y; Vs[rr][cc + 2] = vv.z; Vs[rr][cc + 3] = vv.w;
    }
    __syncthreads();
    float psum = 0.f;
#pragma unroll
    for (int j = 0; j < 4; ++j) {
      int kk = kb4 + j;
      int kglob = kc + kk;
      float s = 0.f;
#pragma unroll
      for (int d = 0; d < 64; ++d) s += Qs[q][d] * Ks[kk][d];
      float pp = (kglob <= qt) ? expf(s) : 0.f;
      Ps[q][kk] = pp;
      psum += pp;
    }
#pragma unroll
    for (int m = 1; m < 16; m <<= 1) psum += __shfl_xor(psum, m, 64);
    denom += psum;
    __syncthreads();
#pragma unroll 8
    for (int kk = 0; kk < 64; ++kk) {
      float pp = Ps[q][kk];
      o0 += pp * Vs[kk][kb4 + 0];
      o1 += pp * Vs[kk][kb4 + 1];
      o2 += pp * Vs[kk][kb4 + 2];
      o3 += pp * Vs[kk][kb4 + 3];
    }
    __syncthreads();
  }
  float invd = 1.0f / denom;
  size_t oidx = ((size_t)(b * TT + qt) * (HH * 64)) + hh * 64 + kb4;
  float4 ov;
  ov.x = o0 * invd; ov.y = o1 * invd; ov.z = o2 * invd; ov.w = o3 * invd;
  *reinterpret_cast<float4*>(O + oidx) = ov;
}

// ---------------------------------------------------------------- causal depthwise conv (CK=4) + silu + split
__global__ __launch_bounds__(256) void conv_k(const float* __restrict__ X,
                                              const float* __restrict__ Wc,
                                              float* __restrict__ Qo,
                                              float* __restrict__ Ko,
                                              float* __restrict__ Vo) {
  int idx = blockIdx.x * 256 + threadIdx.x;   // B*T*3072 exact
  int c = idx % 3072;
  int rest = idx / 3072;
  int t = rest & (TT - 1);
  int b = rest >> 10;
  const float* w = Wc + c * 4;
  float acc = 0.f;
#pragma unroll
  for (int j = 0; j < 4; ++j) {
    int tt = t - 3 + j;
    if (tt >= 0) acc += w[j] * X[((size_t)(b * TT + tt)) * 3072 + c];
  }
  float y = acc / (1.f + expf(-acc));   // silu
  int which = c >> 10, cc = c & 1023;
  float* dst = (which == 0) ? Qo : ((which == 1) ? Ko : Vo);
  dst[((size_t)(b * TT + t)) * 1024 + cc] = y;
}

// ---------------------------------------------------------------- GDN scan v3
// One block (64 threads) per (b,h,vgrp). Lane = vloc*4 + dgrp.
// DPP quad-perm reductions (VALU latency) + unroll-2 ping-pong prefetch
// (no register-copy tail, no ds_bpermute anywhere).
__global__ __launch_bounds__(64) void gdn_scan_k(const float* __restrict__ Qg,
                                                 const float* __restrict__ Kg,
                                                 const float* __restrict__ Vg,
                                                 const float* __restrict__ Al,
                                                 const float* __restrict__ Be,
                                                 float* __restrict__ Og) {
  const int bh = blockIdx.x >> 2;        // b*16+h
  const int vgrp = blockIdx.x & 3;
  const int lane = threadIdx.x;
  const int vloc = lane >> 2;            // 0..15
  const int dgrp = lane & 3;             // 0..3
  const int v = vgrp * 16 + vloc;
  const int b = bh >> 4, hh = bh & 15;
  const int d0 = dgrp * 16;

  float S[16];
#pragma unroll
  for (int i = 0; i < 16; ++i) S[i] = 0.f;

  const size_t base = (size_t)b * TT * 1024 + hh * 64;
  const size_t ab0 = (size_t)b * TT * HH + hh;

  float kA[16], qA[16], kB[16], qB[16];
  float vA, aA, btA, vB, aB, btB;

#define LOADBUF(KX, QX, VX, AX, BX, tt)                                        \
  {                                                                            \
    const float* kp = Kg + base + (size_t)(tt) * 1024 + d0;                    \
    const float* qp = Qg + base + (size_t)(tt) * 1024 + d0;                    \
    _Pragma("unroll") for (int i = 0; i < 4; ++i) {                            \
      float4 kv = *reinterpret_cast<const float4*>(kp + i * 4);                \
      KX[4 * i] = kv.x; KX[4 * i + 1] = kv.y;                                  \
      KX[4 * i + 2] = kv.z; KX[4 * i + 3] = kv.w;                              \
      float4 qv = *reinterpret_cast<const float4*>(qp + i * 4);                \
      QX[4 * i] = qv.x; QX[4 * i + 1] = qv.y;                                  \
      QX[4 * i + 2] = qv.z; QX[4 * i + 3] = qv.w;                              \
    }                                                                          \
    VX = Vg[base + (size_t)(tt) * 1024 + v];                                   \
    AX = Al[ab0 + (size_t)(tt) * HH];                                          \
    BX = Be[ab0 + (size_t)(tt) * HH];                                          \
  }

#define STEP(KX, QX, VX, AX, BX, tt)                                           \
  {                                                                            \
    float t0 = 0.f, t1 = 0.f, t2 = 0.f, t3 = 0.f;                              \
    _Pragma("unroll") for (int i = 0; i < 16; i += 4) {                        \
      t0 += KX[i] * S[i];                                                      \
      t1 += KX[i + 1] * S[i + 1];                                              \
      t2 += KX[i + 2] * S[i + 2];                                              \
      t3 += KX[i + 3] * S[i + 3];                                              \
    }                                                                          \
    float ks = qadd4((t0 + t1) + (t2 + t3));                                   \
    float c = VX - AX * BX * ks;                                               \
    float o0 = 0.f, o1 = 0.f, o2 = 0.f, o3 = 0.f;                              \
    _Pragma("unroll") for (int i = 0; i < 16; i += 4) {                        \
      S[i] = AX * S[i] + c * KX[i];             o0 += QX[i] * S[i];            \
      S[i + 1] = AX * S[i + 1] + c * KX[i + 1]; o1 += QX[i + 1] * S[i + 1];    \
      S[i + 2] = AX * S[i + 2] + c * KX[i + 2]; o2 += QX[i + 2] * S[i + 2];    \
      S[i + 3] = AX * S[i + 3] + c * KX[i + 3]; o3 += QX[i + 3] * S[i + 3];    \
    }                                                                          \
    float o = qadd4((o0 + o1) + (o2 + o3));                                    \
    if (dgrp == 0) Og[base + (size_t)(tt) * 1024 + v] = o;                     \
  }

  LOADBUF(kA, qA, vA, aA, btA, 0);
  for (int t = 0; t < TT; t += 2) {
    LOADBUF(kB, qB, vB, aB, btB, t + 1);       // t+1 <= TT-1 always
    STEP(kA, qA, vA, aA, btA, t);
    if (t + 2 < TT) LOADBUF(kA, qA, vA, aA, btA, t + 2);
    STEP(kB, qB, vB, aB, btB, t + 1);
  }
#undef LOADBUF
#undef STEP
}

// ---------------------------------------------------------------- rmsnorm over 64 * gate (in place)
__global__ __launch_bounds__(256) void rms64_mul_k(float* __restrict__ O,
                                                   const float* __restrict__ G) {
  int row = blockIdx.x * 4 + (threadIdx.x >> 6);
  int lane = threadIdx.x & 63;
  size_t idx = (size_t)row * 64 + lane;
  float val = O[idx];
  float ss = val * val;
#pragma unroll
  for (int m = 1; m < 64; m <<= 1) ss += __shfl_xor(ss, m, 64);
  float sc = rsqrtf(ss * (1.0f / 64.0f) + 1e-6f);
  O[idx] = val * sc * G[idx];
}

// ---------------------------------------------------------------- host-side launch
static inline void gemm(hipStream_t s, const float* A, const float* W, float* C,
                        int M, int N, int K, int ldC, int act, int res) {
  if ((N % 128 == 0) && (K % 32 == 0) && (M % 128 == 0)) {
    dim3 g(N / 128, M / 128);
    mfma_gemm_k<<<g, 256, 0, s>>>(A, W, C, M, N, K, ldC, act, res);
  } else {
    dim3 g((N + 63) / 64, (M + 63) / 64);
    sgemm_k<<<g, 256, 0, s>>>(A, W, C, M, N, K, ldC, act, res);
  }
}

extern "C" void kernel_launch(void* const* d_in, const int* in_sizes, int n_in,
                              void* d_out, int out_size, void* d_ws, size_t ws_size,
                              hipStream_t stream) {
  const int*   tokens = (const int*)d_in[0];
  const float* emb    = (const float*)d_in[1];
  const float* aw_q   = (const float*)d_in[2];
  const float* aw_k   = (const float*)d_in[3];
  const float* aw_v   = (const float*)d_in[4];
  const float* aw_o   = (const float*)d_in[5];
  const float* a_gain = (const float*)d_in[6];
  const float* a_m1   = (const float*)d_in[7];
  const float* a_m2   = (const float*)d_in[8];
  const float* g_wq   = (const float*)d_in[9];
  const float* g_wk   = (const float*)d_in[10];
  const float* g_wv   = (const float*)d_in[11];
  const float* g_wa   = (const float*)d_in[12];
  const float* g_wb   = (const float*)d_in[13];
  const float* g_wg   = (const float*)d_in[14];
  const float* g_wo   = (const float*)d_in[15];
  const float* g_conv = (const float*)d_in[16];
  const float* g_m1   = (const float*)d_in[17];
  const float* g_m2   = (const float*)d_in[18];

  const int M = BB * TT;  // 2048

  float* ws = (float*)d_ws;
  float* x    = ws;                  // 2097152
  float* h    = x + 2097152;         // 2097152
  float* qb   = h + 2097152;         // 2097152 (attn q)
  float* kb   = qb + 2097152;        // 524288  (attn k)
  float* vb   = kb + 524288;         // 524288  (attn v)
  float* qg   = vb + 524288;         // 2097152 (gdn q / attn o_flat)
  float* kg   = qg + 2097152;        // 2097152
  float* vg   = kg + 2097152;        // 2097152
  float* og   = vg + 2097152;        // 2097152
  float* gb   = og + 2097152;        // 2097152
  float* alp  = gb + 2097152;        // 32768
  float* bet  = alp + 32768;         // 32768
  float* cosT = bet + 32768;         // 32768
  float* sinT = cosT + 32768;        // 32768

  // big scratch lives in d_out (fully rewritten by the final logits GEMM)
  float* outF = (float*)d_out;
  float* mid  = outF;                // 8388608  (B*T*DFF)
  float* qkv  = outF + 8388608;      // 6291456  (B*T*3072)

  rope_tab_k<<<128, 256, 0, stream>>>(cosT, sinT);
  embed_k<<<M, 256, 0, stream>>>(tokens, emb, x);

  for (int i = 0; i < 2; ++i) {
    const float* wq = aw_q + (size_t)i * 1024 * 1024;
    const float* wk = aw_k + (size_t)i * 256 * 1024;
    const float* wv = aw_v + (size_t)i * 256 * 1024;
    const float* wo = aw_o + (size_t)i * 1024 * 1024;
    const float* gn = a_gain + (size_t)i * 16;
    const float* m1 = a_m1 + (size_t)i * 4096 * 1024;
    const float* m2 = a_m2 + (size_t)i * 1024 * 4096;
    const float* zq = g_wq + (size_t)i * 1024 * 1024;
    const float* zk = g_wk + (size_t)i * 1024 * 1024;
    const float* zv = g_wv + (size_t)i * 1024 * 1024;
    const float* za = g_wa + (size_t)i * 16 * 1024;
    const float* zb = g_wb + (size_t)i * 16 * 1024;
    const float* zg = g_wg + (size_t)i * 1024 * 1024;
    const float* zo = g_wo + (size_t)i * 1024 * 1024;
    const float* zc = g_conv + (size_t)i * 3072 * 4;
    const float* n1 = g_m1 + (size_t)i * 4096 * 1024;
    const float* n2 = g_m2 + (size_t)i * 1024 * 4096;

    // ---------------- attention block ----------------
    rmsnorm_k<<<M, 256, 0, stream>>>(x, h);
    gemm(stream, h, wq, qb, M, 1024, 1024, 1024, ACT_NONE, 0);
    gemm(stream, h, wk, kb, M, 256, 1024, 256, ACT_NONE, 0);
    gemm(stream, h, wv, vb, M, 256, 1024, 256, ACT_NONE, 0);
    l2n_rope_k<<<(M * HH) / 4, 256, 0, stream>>>(qb, HH, gn, cosT, sinT, 1);
    l2n_rope_k<<<(M * KVH) / 4, 256, 0, stream>>>(kb, KVH, nullptr, cosT, sinT, 1);
    attn_k<<<dim3(TT / 16, BB * HH), 256, 0, stream>>>(qb, kb, vb, qg);
    gemm(stream, qg, wo, x, M, 1024, 1024, 1024, ACT_NONE, 1);
    rmsnorm_k<<<M, 256, 0, stream>>>(x, h);
    gemm(stream, h, m1, mid, M, DFF, 1024, DFF, ACT_RELU2, 0);
    gemm(stream, mid, m2, x, M, 1024, DFF, 1024, ACT_NONE, 1);

    // ---------------- GDN block ----------------
    rmsnorm_k<<<M, 256, 0, stream>>>(x, h);
    gemm(stream, h, zq, qkv + 0,    M, 1024, 1024, 3072, ACT_NONE, 0);
    gemm(stream, h, zk, qkv + 1024, M, 1024, 1024, 3072, ACT_NONE, 0);
    gemm(stream, h, zv, qkv + 2048, M, 1024, 1024, 3072, ACT_NONE, 0);
    conv_k<<<(M * 3072) / 256, 256, 0, stream>>>(qkv, zc, qg, kg, vg);
    l2n_rope_k<<<(M * HH) / 4, 256, 0, stream>>>(qg, HH, nullptr, nullptr, nullptr, 0);
    l2n_rope_k<<<(M * HH) / 4, 256, 0, stream>>>(kg, HH, nullptr, nullptr, nullptr, 0);
    gemm(stream, h, za, alp, M, 16, 1024, 16, ACT_SIG, 0);
    gemm(stream, h, zb, bet, M, 16, 1024, 16, ACT_SIG, 0);
    gdn_scan_k<<<BB * HH * 4, 64, 0, stream>>>(qg, kg, vg, alp, bet, og);
    gemm(stream, h, zg, gb, M, 1024, 1024, 1024, ACT_SILU, 0);
    rms64_mul_k<<<(M * HH) / 4, 256, 0, stream>>>(og, gb);
    gemm(stream, og, zo, x, M, 1024, 1024, 1024, ACT_NONE, 1);
    rmsnorm_k<<<M, 256, 0, stream>>>(x, h);
    gemm(stream, h, n1, mid, M, DFF, 1024, DFF, ACT_RELU2, 0);
    gemm(stream, mid, n2, x, M, 1024, DFF, 1024, ACT_NONE, 1);
  }

  // ---------------- final logits ----------------
  rmsnorm_k<<<M, 256, 0, stream>>>(x, h);
  gemm(stream, h, emb, outF, M, VV, 1024, VV, ACT_NONE, 0);
}

// Round 5
// 3786.662 us; speedup vs baseline: 2.7226x; 1.2242x over previous
//
#include <hip/hip_runtime.h>
#include <hip/hip_bf16.h>
#include <math.h>

// ---------------------------------------------------------------- constants
#define BB 2
#define TT 1024
#define DD 1024
#define HH 16
#define KVH 4
#define HDIM 64
#define VV 32768
#define DFF 4096

#define ACT_NONE 0
#define ACT_RELU2 1
#define ACT_SILU 2
#define ACT_SIG 3

typedef __attribute__((ext_vector_type(8))) short short8v;
typedef __attribute__((ext_vector_type(4))) float f32x4;

__device__ inline ushort f2bf(float f) {
  uint u = __float_as_uint(f);
  uint r = u + 0x7FFFu + ((u >> 16) & 1u);
  return (ushort)(r >> 16);
}
__device__ inline uint pack2(float lo, float hi) {
  return (uint)f2bf(lo) | ((uint)f2bf(hi) << 16);
}

// 4-lane (quad) sum via DPP quad_perm: xor1 (0xB1) then xor2 (0x4E). VALU-speed.
__device__ inline float qadd4(float x) {
  float y = __int_as_float(__builtin_amdgcn_update_dpp(
      0, __float_as_int(x), 0xB1, 0xF, 0xF, true));
  x += y;
  float z = __int_as_float(__builtin_amdgcn_update_dpp(
      0, __float_as_int(x), 0x4E, 0xF, 0xF, true));
  return x + z;
}

// ---------------------------------------------------------------- rope tables
__global__ __launch_bounds__(256) void rope_tab_k(float* __restrict__ cosT,
                                                  float* __restrict__ sinT) {
  int idx = blockIdx.x * 256 + threadIdx.x;   // T*32 = 32768 total
  int t = idx >> 5, j = idx & 31;
  float inv = 1.0f / powf(10000.0f, (float)(2 * j) * (1.0f / 64.0f));
  float fr = (float)t * inv;
  cosT[idx] = cosf(fr);
  sinT[idx] = sinf(fr);
}

// ---------------------------------------------------------------- embedding gather
__global__ __launch_bounds__(256) void embed_k(const int* __restrict__ tok,
                                               const float* __restrict__ emb,
                                               float* __restrict__ X) {
  int row = blockIdx.x;          // B*T rows
  int tid = threadIdx.x;
  int tk = tok[row];
  float4 v = *reinterpret_cast<const float4*>(emb + (size_t)tk * DD + tid * 4);
  *reinterpret_cast<float4*>(X + (size_t)row * DD + tid * 4) = v;
}

// ---------------------------------------------------------------- rmsnorm over D=1024
__global__ __launch_bounds__(256) void rmsnorm_k(const float* __restrict__ in,
                                                 float* __restrict__ out) {
  int row = blockIdx.x;
  int tid = threadIdx.x;
  const float* p = in + (size_t)row * DD;
  float4 v = *reinterpret_cast<const float4*>(p + tid * 4);
  float ss = v.x * v.x + v.y * v.y + v.z * v.z + v.w * v.w;
#pragma unroll
  for (int m = 1; m < 64; m <<= 1) ss += __shfl_xor(ss, m, 64);
  __shared__ float wsum[4];
  int wid = tid >> 6, lane = tid & 63;
  if (lane == 0) wsum[wid] = ss;
  __syncthreads();
  float tot = wsum[0] + wsum[1] + wsum[2] + wsum[3];
  float sc = rsqrtf(tot * (1.0f / 1024.0f) + 1e-6f);
  float4 o;
  o.x = v.x * sc; o.y = v.y * sc; o.z = v.z * sc; o.w = v.w * sc;
  *reinterpret_cast<float4*>(out + (size_t)row * DD + tid * 4) = o;
}

// ---------------------------------------------------------------- MFMA bf16 GEMM: C = [res +] act(A @ W^T)
__global__ __launch_bounds__(256) void mfma_gemm_k(const float* __restrict__ A,
                                                   const float* __restrict__ W,
                                                   float* __restrict__ C,
                                                   int M, int N, int K, int ldC,
                                                   int act, int res) {
  __shared__ ushort As[128 * 40];   // row stride 40 bf16 (80B) to spread banks
  __shared__ ushort Ws[128 * 40];
  const int bm = blockIdx.y * 128;
  const int bn = blockIdx.x * 128;
  const int tid = threadIdx.x;
  const int wave = tid >> 6, lane = tid & 63;
  const int wr = wave >> 1, wc = wave & 1;
  const int lr = lane & 15, lk = (lane >> 4) * 8;   // frag row-in-tile, k-base

  const int srow = tid >> 3;        // 0..31
  const int scol = (tid & 7) * 4;   // 0..28

  f32x4 acc[4][4] = {};

  for (int k0 = 0; k0 < K; k0 += 32) {
#pragma unroll
    for (int p = 0; p < 4; ++p) {
      int row = p * 32 + srow;
      float4 av = *reinterpret_cast<const float4*>(A + (size_t)(bm + row) * K + k0 + scol);
      uint2 aw; aw.x = pack2(av.x, av.y); aw.y = pack2(av.z, av.w);
      *reinterpret_cast<uint2*>(&As[row * 40 + scol]) = aw;
      float4 wv = *reinterpret_cast<const float4*>(W + (size_t)(bn + row) * K + k0 + scol);
      uint2 ww; ww.x = pack2(wv.x, wv.y); ww.y = pack2(wv.z, wv.w);
      *reinterpret_cast<uint2*>(&Ws[row * 40 + scol]) = ww;
    }
    __syncthreads();
    short8v av[4], bv[4];
#pragma unroll
    for (int m = 0; m < 4; ++m)
      av[m] = *reinterpret_cast<const short8v*>(&As[(wr * 64 + m * 16 + lr) * 40 + lk]);
#pragma unroll
    for (int n = 0; n < 4; ++n)
      bv[n] = *reinterpret_cast<const short8v*>(&Ws[(wc * 64 + n * 16 + lr) * 40 + lk]);
#pragma unroll
    for (int m = 0; m < 4; ++m)
#pragma unroll
      for (int n = 0; n < 4; ++n)
        acc[m][n] = __builtin_amdgcn_mfma_f32_16x16x32_bf16(av[m], bv[n], acc[m][n], 0, 0, 0);
    __syncthreads();
  }

  const int rj = (lane >> 4) * 4;
#pragma unroll
  for (int m = 0; m < 4; ++m) {
    int rowb = bm + wr * 64 + m * 16 + rj;
#pragma unroll
    for (int n = 0; n < 4; ++n) {
      int col = bn + wc * 64 + n * 16 + lr;
#pragma unroll
      for (int j = 0; j < 4; ++j) {
        float v = acc[m][n][j];
        if (act == ACT_RELU2) { v = fmaxf(v, 0.f); v = v * v; }
        else if (act == ACT_SILU) { v = v / (1.f + expf(-v)); }
        float* cp = C + (size_t)(rowb + j) * ldC + col;
        if (res) v += *cp;
        *cp = v;
      }
    }
  }
}

// ---------------------------------------------------------------- fp32 SGEMM (small N fallback)
__global__ __launch_bounds__(256) void sgemm_k(const float* __restrict__ A,
                                               const float* __restrict__ W,
                                               float* __restrict__ C,
                                               int M, int N, int K, int ldC,
                                               int act, int res) {
  __shared__ float Asm[16][65];
  __shared__ float Wsm[16][65];
  const int bm = blockIdx.y * 64;
  const int bn = blockIdx.x * 64;
  const int tid = threadIdx.x;
  const int tx = tid & 15, ty = tid >> 4;
  const int lr = tid >> 2;          // 0..63
  const int lc = (tid & 3) * 4;     // 0,4,8,12
  float acc[4][4] = {{0.f}};
  for (int k0 = 0; k0 < K; k0 += 16) {
    int arow = bm + lr;
    float4 av = make_float4(0.f, 0.f, 0.f, 0.f);
    if (arow < M) av = *reinterpret_cast<const float4*>(A + (size_t)arow * K + k0 + lc);
    Asm[lc + 0][lr] = av.x; Asm[lc + 1][lr] = av.y; Asm[lc + 2][lr] = av.z; Asm[lc + 3][lr] = av.w;
    int wrow = bn + lr;
    float4 wv = make_float4(0.f, 0.f, 0.f, 0.f);
    if (wrow < N) wv = *reinterpret_cast<const float4*>(W + (size_t)wrow * K + k0 + lc);
    Wsm[lc + 0][lr] = wv.x; Wsm[lc + 1][lr] = wv.y; Wsm[lc + 2][lr] = wv.z; Wsm[lc + 3][lr] = wv.w;
    __syncthreads();
#pragma unroll
    for (int kk = 0; kk < 16; ++kk) {
      float a[4], b[4];
#pragma unroll
      for (int i = 0; i < 4; ++i) a[i] = Asm[kk][ty * 4 + i];
#pragma unroll
      for (int j = 0; j < 4; ++j) b[j] = Wsm[kk][tx * 4 + j];
#pragma unroll
      for (int i = 0; i < 4; ++i)
#pragma unroll
        for (int j = 0; j < 4; ++j) acc[i][j] += a[i] * b[j];
    }
    __syncthreads();
  }
#pragma unroll
  for (int i = 0; i < 4; ++i) {
    int row = bm + ty * 4 + i;
    if (row >= M) continue;
#pragma unroll
    for (int j = 0; j < 4; ++j) {
      int col = bn + tx * 4 + j;
      if (col >= N) continue;
      float v = acc[i][j];
      if (act == ACT_RELU2) { v = fmaxf(v, 0.f); v = v * v; }
      else if (act == ACT_SILU) { v = v / (1.f + expf(-v)); }
      else if (act == ACT_SIG) { v = 1.f / (1.f + expf(-v)); }
      float* cp = C + (size_t)row * ldC + col;
      if (res) v += *cp;
      *cp = v;
    }
  }
}

// ---------------------------------------------------------------- l2norm (+gain) (+rope) on rows of 64
__global__ __launch_bounds__(256) void l2n_rope_k(float* __restrict__ P, int NH,
                                                  const float* __restrict__ gain,
                                                  const float* __restrict__ cosT,
                                                  const float* __restrict__ sinT,
                                                  int do_rope) {
  int row = blockIdx.x * 4 + (threadIdx.x >> 6);
  int lane = threadIdx.x & 63;
  size_t idx = (size_t)row * 64 + lane;
  float val = P[idx];
  float ss = val * val;
#pragma unroll
  for (int m = 1; m < 64; m <<= 1) ss += __shfl_xor(ss, m, 64);
  val = val / fmaxf(sqrtf(ss), 1e-6f);
  int hh = row % NH;
  int t = (row / NH) & (TT - 1);
  if (gain) val *= gain[hh];
  if (do_rope) {
    float pr = __shfl_xor(val, 32, 64);
    int jj = lane & 31;
    float c = cosT[t * 32 + jj];
    float s = sinT[t * 32 + jj];
    val = (lane < 32) ? (val * c + pr * s) : (val * c - pr * s);
  }
  P[idx] = val;
}

// ---------------------------------------------------------------- MFMA flash attention
// grid (T/64, B*H), 256 threads = 4 waves; wave owns 16 query rows.
// K staged row-major bf16, V staged transposed (Vt[d][key]); P round-trips
// through per-wave LDS to convert C-layout -> A-frag layout. Row sums via
// MFMA against all-ones B (col-replicated, matches O frag row layout).
__global__ __launch_bounds__(256) void attn_mfma_k(const float* __restrict__ Q,
                                                   const float* __restrict__ K,
                                                   const float* __restrict__ V,
                                                   float* __restrict__ O) {
  __shared__ ushort Ks[64 * 72];
  __shared__ ushort Vt[64 * 72];
  __shared__ ushort Ps[4][16 * 72];

  const int q0 = blockIdx.x * 64;
  const int bh = blockIdx.y;
  const int b = bh >> 4, hh = bh & 15;
  const int kvh = hh >> 2;
  const int tid = threadIdx.x;
  const int wave = tid >> 6, lane = tid & 63;
  const int l15 = lane & 15, l16 = lane >> 4;   // 0..15 / 0..3
  const int rj = l16 * 4;

  const int qrs = HH * 64;    // 1024
  const int krs = KVH * 64;   // 256
  const float* Qb = Q + (size_t)b * TT * qrs + hh * 64;
  const float* Kb = K + (size_t)b * TT * krs + kvh * 64;
  const float* Vb = V + (size_t)b * TT * krs + kvh * 64;
  float* Ob = O + (size_t)b * TT * qrs + hh * 64;

  // Q A-frags (row = l15, k(d) = l16*8 + i, dblk in {0,+32})
  short8v qa[2];
  {
    const float* qp = Qb + (size_t)(q0 + wave * 16 + l15) * qrs + l16 * 8;
#pragma unroll
    for (int dblk = 0; dblk < 2; ++dblk) {
      float4 x = *reinterpret_cast<const float4*>(qp + dblk * 32);
      float4 y = *reinterpret_cast<const float4*>(qp + dblk * 32 + 4);
      union { short8v v; uint u[4]; } tmp;
      tmp.u[0] = pack2(x.x, x.y); tmp.u[1] = pack2(x.z, x.w);
      tmp.u[2] = pack2(y.x, y.y); tmp.u[3] = pack2(y.z, y.w);
      qa[dblk] = tmp.v;
    }
  }

  short8v ones;
  { union { short8v v; uint u[4]; } t;
    t.u[0] = t.u[1] = t.u[2] = t.u[3] = 0x3F803F80u; ones = t.v; }

  f32x4 o[4] = {};
  f32x4 denom = {};

  const int skey = tid >> 2;          // staging key 0..63
  const int sd   = (tid & 3) * 16;    // staging d base

  for (int kc = 0; kc <= q0; kc += 64) {
    __syncthreads();
    {
      const float* kp = Kb + (size_t)(kc + skey) * krs + sd;
      const float* vp = Vb + (size_t)(kc + skey) * krs + sd;
#pragma unroll
      for (int c = 0; c < 4; ++c) {
        float4 kv = *reinterpret_cast<const float4*>(kp + c * 4);
        uint2 kw; kw.x = pack2(kv.x, kv.y); kw.y = pack2(kv.z, kv.w);
        *reinterpret_cast<uint2*>(&Ks[skey * 72 + sd + c * 4]) = kw;
        float4 vv = *reinterpret_cast<const float4*>(vp + c * 4);
        Vt[(sd + c * 4 + 0) * 72 + skey] = f2bf(vv.x);
        Vt[(sd + c * 4 + 1) * 72 + skey] = f2bf(vv.y);
        Vt[(sd + c * 4 + 2) * 72 + skey] = f2bf(vv.z);
        Vt[(sd + c * 4 + 3) * 72 + skey] = f2bf(vv.w);
      }
    }
    __syncthreads();

    // S = Q @ K^T (16q x 64k)
    f32x4 s[4];
#pragma unroll
    for (int kb = 0; kb < 4; ++kb) {
      short8v k0 = *reinterpret_cast<const short8v*>(&Ks[(kb * 16 + l15) * 72 + l16 * 8]);
      short8v k1 = *reinterpret_cast<const short8v*>(&Ks[(kb * 16 + l15) * 72 + 32 + l16 * 8]);
      f32x4 z = {};
      z = __builtin_amdgcn_mfma_f32_16x16x32_bf16(qa[0], k0, z, 0, 0, 0);
      s[kb] = __builtin_amdgcn_mfma_f32_16x16x32_bf16(qa[1], k1, z, 0, 0, 0);
    }

    // causal mask + exp (scores in [-1.5,1.5]: no max-sub needed) -> Ps bf16
    const int qg = q0 + wave * 16 + rj;
#pragma unroll
    for (int kb = 0; kb < 4; ++kb) {
      int key = kc + kb * 16 + l15;
#pragma unroll
      for (int j = 0; j < 4; ++j) {
        float p = (key <= qg + j) ? __expf(s[kb][j]) : 0.f;
        Ps[wave][(rj + j) * 72 + kb * 16 + l15] = f2bf(p);
      }
    }

    // P A-frags (row = l15, k = key)
    short8v pa0 = *reinterpret_cast<const short8v*>(&Ps[wave][l15 * 72 + l16 * 8]);
    short8v pa1 = *reinterpret_cast<const short8v*>(&Ps[wave][l15 * 72 + 32 + l16 * 8]);

    // denom += rowsum(P) via ones-B MFMA (col-replicated)
    f32x4 dz = {};
    dz = __builtin_amdgcn_mfma_f32_16x16x32_bf16(pa0, ones, dz, 0, 0, 0);
    dz = __builtin_amdgcn_mfma_f32_16x16x32_bf16(pa1, ones, dz, 0, 0, 0);
    denom += dz;

    // O += P @ V
#pragma unroll
    for (int db = 0; db < 4; ++db) {
      short8v v0 = *reinterpret_cast<const short8v*>(&Vt[(db * 16 + l15) * 72 + l16 * 8]);
      short8v v1 = *reinterpret_cast<const short8v*>(&Vt[(db * 16 + l15) * 72 + 32 + l16 * 8]);
      o[db] = __builtin_amdgcn_mfma_f32_16x16x32_bf16(pa0, v0, o[db], 0, 0, 0);
      o[db] = __builtin_amdgcn_mfma_f32_16x16x32_bf16(pa1, v1, o[db], 0, 0, 0);
    }
  }

  const int qg = q0 + wave * 16 + rj;
#pragma unroll
  for (int j = 0; j < 4; ++j) {
    float inv = 1.0f / denom[j];
    float* op = Ob + (size_t)(qg + j) * qrs;
#pragma unroll
    for (int db = 0; db < 4; ++db) op[db * 16 + l15] = o[db][j] * inv;
  }
}

// ---------------------------------------------------------------- causal depthwise conv (CK=4) + silu + split
__global__ __launch_bounds__(256) void conv_k(const float* __restrict__ X,
                                              const float* __restrict__ Wc,
                                              float* __restrict__ Qo,
                                              float* __restrict__ Ko,
                                              float* __restrict__ Vo) {
  int idx = blockIdx.x * 256 + threadIdx.x;   // B*T*3072 exact
  int c = idx % 3072;
  int rest = idx / 3072;
  int t = rest & (TT - 1);
  int b = rest >> 10;
  const float* w = Wc + c * 4;
  float acc = 0.f;
#pragma unroll
  for (int j = 0; j < 4; ++j) {
    int tt = t - 3 + j;
    if (tt >= 0) acc += w[j] * X[((size_t)(b * TT + tt)) * 3072 + c];
  }
  float y = acc / (1.f + expf(-acc));   // silu
  int which = c >> 10, cc = c & 1023;
  float* dst = (which == 0) ? Qo : ((which == 1) ? Ko : Vo);
  dst[((size_t)(b * TT + t)) * 1024 + cc] = y;
}

// ---------------------------------------------------------------- GDN scan v3
__global__ __launch_bounds__(64) void gdn_scan_k(const float* __restrict__ Qg,
                                                 const float* __restrict__ Kg,
                                                 const float* __restrict__ Vg,
                                                 const float* __restrict__ Al,
                                                 const float* __restrict__ Be,
                                                 float* __restrict__ Og) {
  const int bh = blockIdx.x >> 2;        // b*16+h
  const int vgrp = blockIdx.x & 3;
  const int lane = threadIdx.x;
  const int vloc = lane >> 2;            // 0..15
  const int dgrp = lane & 3;             // 0..3
  const int v = vgrp * 16 + vloc;
  const int b = bh >> 4, hh = bh & 15;
  const int d0 = dgrp * 16;

  float S[16];
#pragma unroll
  for (int i = 0; i < 16; ++i) S[i] = 0.f;

  const size_t base = (size_t)b * TT * 1024 + hh * 64;
  const size_t ab0 = (size_t)b * TT * HH + hh;

  float kA[16], qA[16], kB[16], qB[16];
  float vA, aA, btA, vB, aB, btB;

#define LOADBUF(KX, QX, VX, AX, BX, tt)                                        \
  {                                                                            \
    const float* kp = Kg + base + (size_t)(tt) * 1024 + d0;                    \
    const float* qp = Qg + base + (size_t)(tt) * 1024 + d0;                    \
    _Pragma("unroll") for (int i = 0; i < 4; ++i) {                            \
      float4 kv = *reinterpret_cast<const float4*>(kp + i * 4);                \
      KX[4 * i] = kv.x; KX[4 * i + 1] = kv.y;                                  \
      KX[4 * i + 2] = kv.z; KX[4 * i + 3] = kv.w;                              \
      float4 qv = *reinterpret_cast<const float4*>(qp + i * 4);                \
      QX[4 * i] = qv.x; QX[4 * i + 1] = qv.y;                                  \
      QX[4 * i + 2] = qv.z; QX[4 * i + 3] = qv.w;                              \
    }                                                                          \
    VX = Vg[base + (size_t)(tt) * 1024 + v];                                   \
    AX = Al[ab0 + (size_t)(tt) * HH];                                          \
    BX = Be[ab0 + (size_t)(tt) * HH];                                          \
  }

#define STEP(KX, QX, VX, AX, BX, tt)                                           \
  {                                                                            \
    float t0 = 0.f, t1 = 0.f, t2 = 0.f, t3 = 0.f;                              \
    _Pragma("unroll") for (int i = 0; i < 16; i += 4) {                        \
      t0 += KX[i] * S[i];                                                      \
      t1 += KX[i + 1] * S[i + 1];                                              \
      t2 += KX[i + 2] * S[i + 2];                                              \
      t3 += KX[i + 3] * S[i + 3];                                              \
    }                                                                          \
    float ks = qadd4((t0 + t1) + (t2 + t3));                                   \
    float c = VX - AX * BX * ks;                                               \
    float o0 = 0.f, o1 = 0.f, o2 = 0.f, o3 = 0.f;                              \
    _Pragma("unroll") for (int i = 0; i < 16; i += 4) {                        \
      S[i] = AX * S[i] + c * KX[i];             o0 += QX[i] * S[i];            \
      S[i + 1] = AX * S[i + 1] + c * KX[i + 1]; o1 += QX[i + 1] * S[i + 1];    \
      S[i + 2] = AX * S[i + 2] + c * KX[i + 2]; o2 += QX[i + 2] * S[i + 2];    \
      S[i + 3] = AX * S[i + 3] + c * KX[i + 3]; o3 += QX[i + 3] * S[i + 3];    \
    }                                                                          \
    float o = qadd4((o0 + o1) + (o2 + o3));                                    \
    if (dgrp == 0) Og[base + (size_t)(tt) * 1024 + v] = o;                     \
  }

  LOADBUF(kA, qA, vA, aA, btA, 0);
  for (int t = 0; t < TT; t += 2) {
    LOADBUF(kB, qB, vB, aB, btB, t + 1);       // t+1 <= TT-1 always
    STEP(kA, qA, vA, aA, btA, t);
    if (t + 2 < TT) LOADBUF(kA, qA, vA, aA, btA, t + 2);
    STEP(kB, qB, vB, aB, btB, t + 1);
  }
#undef LOADBUF
#undef STEP
}

// ---------------------------------------------------------------- rmsnorm over 64 * gate (in place)
__global__ __launch_bounds__(256) void rms64_mul_k(float* __restrict__ O,
                                                   const float* __restrict__ G) {
  int row = blockIdx.x * 4 + (threadIdx.x >> 6);
  int lane = threadIdx.x & 63;
  size_t idx = (size_t)row * 64 + lane;
  float val = O[idx];
  float ss = val * val;
#pragma unroll
  for (int m = 1; m < 64; m <<= 1) ss += __shfl_xor(ss, m, 64);
  float sc = rsqrtf(ss * (1.0f / 64.0f) + 1e-6f);
  O[idx] = val * sc * G[idx];
}

// ---------------------------------------------------------------- host-side launch
static inline void gemm(hipStream_t s, const float* A, const float* W, float* C,
                        int M, int N, int K, int ldC, int act, int res) {
  if ((N % 128 == 0) && (K % 32 == 0) && (M % 128 == 0)) {
    dim3 g(N / 128, M / 128);
    mfma_gemm_k<<<g, 256, 0, s>>>(A, W, C, M, N, K, ldC, act, res);
  } else {
    dim3 g((N + 63) / 64, (M + 63) / 64);
    sgemm_k<<<g, 256, 0, s>>>(A, W, C, M, N, K, ldC, act, res);
  }
}

extern "C" void kernel_launch(void* const* d_in, const int* in_sizes, int n_in,
                              void* d_out, int out_size, void* d_ws, size_t ws_size,
                              hipStream_t stream) {
  const int*   tokens = (const int*)d_in[0];
  const float* emb    = (const float*)d_in[1];
  const float* aw_q   = (const float*)d_in[2];
  const float* aw_k   = (const float*)d_in[3];
  const float* aw_v   = (const float*)d_in[4];
  const float* aw_o   = (const float*)d_in[5];
  const float* a_gain = (const float*)d_in[6];
  const float* a_m1   = (const float*)d_in[7];
  const float* a_m2   = (const float*)d_in[8];
  const float* g_wq   = (const float*)d_in[9];
  const float* g_wk   = (const float*)d_in[10];
  const float* g_wv   = (const float*)d_in[11];
  const float* g_wa   = (const float*)d_in[12];
  const float* g_wb   = (const float*)d_in[13];
  const float* g_wg   = (const float*)d_in[14];
  const float* g_wo   = (const float*)d_in[15];
  const float* g_conv = (const float*)d_in[16];
  const float* g_m1   = (const float*)d_in[17];
  const float* g_m2   = (const float*)d_in[18];

  const int M = BB * TT;  // 2048

  float* ws = (float*)d_ws;
  float* x    = ws;                  // 2097152
  float* h    = x + 2097152;         // 2097152
  float* qb   = h + 2097152;         // 2097152 (attn q)
  float* kb   = qb + 2097152;        // 524288  (attn k)
  float* vb   = kb + 524288;         // 524288  (attn v)
  float* qg   = vb + 524288;         // 2097152 (gdn q / attn o_flat)
  float* kg   = qg + 2097152;        // 2097152
  float* vg   = kg + 2097152;        // 2097152
  float* og   = vg + 2097152;        // 2097152
  float* gb   = og + 2097152;        // 2097152
  float* alp  = gb + 2097152;        // 32768
  float* bet  = alp + 32768;         // 32768
  float* cosT = bet + 32768;         // 32768
  float* sinT = cosT + 32768;        // 32768

  // big scratch lives in d_out (fully rewritten by the final logits GEMM)
  float* outF = (float*)d_out;
  float* mid  = outF;                // 8388608  (B*T*DFF)
  float* qkv  = outF + 8388608;      // 6291456  (B*T*3072)

  rope_tab_k<<<128, 256, 0, stream>>>(cosT, sinT);
  embed_k<<<M, 256, 0, stream>>>(tokens, emb, x);

  for (int i = 0; i < 2; ++i) {
    const float* wq = aw_q + (size_t)i * 1024 * 1024;
    const float* wk = aw_k + (size_t)i * 256 * 1024;
    const float* wv = aw_v + (size_t)i * 256 * 1024;
    const float* wo = aw_o + (size_t)i * 1024 * 1024;
    const float* gn = a_gain + (size_t)i * 16;
    const float* m1 = a_m1 + (size_t)i * 4096 * 1024;
    const float* m2 = a_m2 + (size_t)i * 1024 * 4096;
    const float* zq = g_wq + (size_t)i * 1024 * 1024;
    const float* zk = g_wk + (size_t)i * 1024 * 1024;
    const float* zv = g_wv + (size_t)i * 1024 * 1024;
    const float* za = g_wa + (size_t)i * 16 * 1024;
    const float* zb = g_wb + (size_t)i * 16 * 1024;
    const float* zg = g_wg + (size_t)i * 1024 * 1024;
    const float* zo = g_wo + (size_t)i * 1024 * 1024;
    const float* zc = g_conv + (size_t)i * 3072 * 4;
    const float* n1 = g_m1 + (size_t)i * 4096 * 1024;
    const float* n2 = g_m2 + (size_t)i * 1024 * 4096;

    // ---------------- attention block ----------------
    rmsnorm_k<<<M, 256, 0, stream>>>(x, h);
    gemm(stream, h, wq, qb, M, 1024, 1024, 1024, ACT_NONE, 0);
    gemm(stream, h, wk, kb, M, 256, 1024, 256, ACT_NONE, 0);
    gemm(stream, h, wv, vb, M, 256, 1024, 256, ACT_NONE, 0);
    l2n_rope_k<<<(M * HH) / 4, 256, 0, stream>>>(qb, HH, gn, cosT, sinT, 1);
    l2n_rope_k<<<(M * KVH) / 4, 256, 0, stream>>>(kb, KVH, nullptr, cosT, sinT, 1);
    attn_mfma_k<<<dim3(TT / 64, BB * HH), 256, 0, stream>>>(qb, kb, vb, qg);
    gemm(stream, qg, wo, x, M, 1024, 1024, 1024, ACT_NONE, 1);
    rmsnorm_k<<<M, 256, 0, stream>>>(x, h);
    gemm(stream, h, m1, mid, M, DFF, 1024, DFF, ACT_RELU2, 0);
    gemm(stream, mid, m2, x, M, 1024, DFF, 1024, ACT_NONE, 1);

    // ---------------- GDN block ----------------
    rmsnorm_k<<<M, 256, 0, stream>>>(x, h);
    gemm(stream, h, zq, qkv + 0,    M, 1024, 1024, 3072, ACT_NONE, 0);
    gemm(stream, h, zk, qkv + 1024, M, 1024, 1024, 3072, ACT_NONE, 0);
    gemm(stream, h, zv, qkv + 2048, M, 1024, 1024, 3072, ACT_NONE, 0);
    conv_k<<<(M * 3072) / 256, 256, 0, stream>>>(qkv, zc, qg, kg, vg);
    l2n_rope_k<<<(M * HH) / 4, 256, 0, stream>>>(qg, HH, nullptr, nullptr, nullptr, 0);
    l2n_rope_k<<<(M * HH) / 4, 256, 0, stream>>>(kg, HH, nullptr, nullptr, nullptr, 0);
    gemm(stream, h, za, alp, M, 16, 1024, 16, ACT_SIG, 0);
    gemm(stream, h, zb, bet, M, 16, 1024, 16, ACT_SIG, 0);
    gdn_scan_k<<<BB * HH * 4, 64, 0, stream>>>(qg, kg, vg, alp, bet, og);
    gemm(stream, h, zg, gb, M, 1024, 1024, 1024, ACT_SILU, 0);
    rms64_mul_k<<<(M * HH) / 4, 256, 0, stream>>>(og, gb);
    gemm(stream, og, zo, x, M, 1024, 1024, 1024, ACT_NONE, 1);
    rmsnorm_k<<<M, 256, 0, stream>>>(x, h);
    gemm(stream, h, n1, mid, M, DFF, 1024, DFF, ACT_RELU2, 0);
    gemm(stream, mid, n2, x, M, 1024, DFF, 1024, ACT_NONE, 1);
  }

  // ---------------- final logits ----------------
  rmsnorm_k<<<M, 256, 0, stream>>>(x, h);
  gemm(stream, h, emb, outF, M, VV, 1024, VV, ACT_NONE, 0);
}